// Round 2
// baseline (6678.546 us; speedup 1.0000x reference)
//
#include <hip/hip_runtime.h>
#include <cstdint>
#include <cstddef>

#define FDIM   128
#define NBASIS 20
#define NLAYERS 3
#define RCUT   5.0f
#define PI_F   3.14159265358979323846f
#define CHUNK  64
#define TPB    512
#define WPAD   132   // 528B rows: 16B-aligned for b128 reads

__device__ __forceinline__ float silu_f(float x) { return x / (1.f + __expf(-x)); }

// Stage W[c][k] (row-major 128x128) transposed into LDS Wt[k][c].
// Global reads fully coalesced (float4); LDS scatter writes are conflicted but
// amortized (32 writes vs 1024 conflict-free reads per GEMM).
__device__ __forceinline__ void stage_wt(const float* __restrict__ W,
                                         float (*Wt)[WPAD], int tid)
{
    #pragma unroll
    for (int i = 0; i < 8; ++i) {
        int p = tid + i*TPB;            // 4096 float4 = 128x128
        int c = p >> 5, k4 = p & 31;
        float4 v = reinterpret_cast<const float4*>(W)[p];
        Wt[k4*4+0][c] = v.x;
        Wt[k4*4+1][c] = v.y;
        Wt[k4*4+2][c] = v.z;
        Wt[k4*4+3][c] = v.w;
    }
}

// acc[i][j] += sum_k src[rg*4+i][k] * Wt[k][cg*4+j]
// a-reads: broadcast within half-wave; w-reads: one contiguous 512B LDS row -> conflict-free.
__device__ __forceinline__ void gemm64(const float (*src)[FDIM],
                                       const float (*Wt)[WPAD],
                                       int rg, int cg, float acc[4][4])
{
    #pragma unroll
    for (int k4 = 0; k4 < FDIM/4; ++k4) {
        float4 a[4];
        #pragma unroll
        for (int i = 0; i < 4; ++i)
            a[i] = *reinterpret_cast<const float4*>(&src[rg*4+i][k4*4]);
        #pragma unroll
        for (int kk = 0; kk < 4; ++kk) {
            float4 w = *reinterpret_cast<const float4*>(&Wt[k4*4+kk][cg*4]);
            #pragma unroll
            for (int i = 0; i < 4; ++i) {
                float av = (kk==0) ? a[i].x : (kk==1) ? a[i].y : (kk==2) ? a[i].z : a[i].w;
                acc[i][0] += av * w.x;
                acc[i][1] += av * w.y;
                acc[i][2] += av * w.z;
                acc[i][3] += av * w.w;
            }
        }
    }
}

// ---------------------------------------------------------------- atom init
__global__ __launch_bounds__(256)
void atom_init_kernel(const int* __restrict__ zc, const float* __restrict__ emb,
                      float* __restrict__ atom, int N)
{
    int t = blockIdx.x * 256 + threadIdx.x;
    if (t >= N * FDIM) return;
    int n = t >> 7, f = t & 127;
    atom[t] = emb[zc[n]*FDIM + f];
}

// ---------------------------------------------------------------- node MLP (with bias)
__global__ __launch_bounds__(TPB)
void node_mlp_kernel(const float* __restrict__ in, float* __restrict__ out,
                     const float* __restrict__ W1, const float* __restrict__ b1,
                     const float* __restrict__ W2, const float* __restrict__ b2,
                     int R)
{
    __shared__ float Wt[FDIM][WPAD];    // 66 KB
    __shared__ float inb[CHUNK][FDIM];  // 32 KB
    __shared__ float hb[CHUNK][FDIM];   // 32 KB
    const int tid = threadIdx.x;
    const int r0  = blockIdx.x * CHUNK;
    const int rg  = tid >> 5, cg = tid & 31;

    {
        const float4* gin = reinterpret_cast<const float4*>(in) + (size_t)r0 * (FDIM/4);
        #pragma unroll
        for (int i = 0; i < 4; ++i) {
            int p = tid + i*TPB;
            int r = p >> 5;
            float4 v = make_float4(0.f,0.f,0.f,0.f);
            if (r0 + r < R) v = gin[p];
            *reinterpret_cast<float4*>(&inb[r][(p & 31)*4]) = v;
        }
    }
    stage_wt(W1, Wt, tid);
    __syncthreads();

    float acc[4][4];
    {
        float4 bv = *reinterpret_cast<const float4*>(b1 + cg*4);
        #pragma unroll
        for (int i = 0; i < 4; ++i) {
            acc[i][0]=bv.x; acc[i][1]=bv.y; acc[i][2]=bv.z; acc[i][3]=bv.w;
        }
    }
    gemm64(inb, Wt, rg, cg, acc);
    #pragma unroll
    for (int i = 0; i < 4; ++i) {
        float4 hv;
        hv.x = silu_f(acc[i][0]); hv.y = silu_f(acc[i][1]);
        hv.z = silu_f(acc[i][2]); hv.w = silu_f(acc[i][3]);
        *reinterpret_cast<float4*>(&hb[rg*4+i][cg*4]) = hv;
    }
    __syncthreads();

    stage_wt(W2, Wt, tid);
    __syncthreads();

    {
        float4 bv = *reinterpret_cast<const float4*>(b2 + cg*4);
        #pragma unroll
        for (int i = 0; i < 4; ++i) {
            acc[i][0]=bv.x; acc[i][1]=bv.y; acc[i][2]=bv.z; acc[i][3]=bv.w;
        }
    }
    gemm64(hb, Wt, rg, cg, acc);

    #pragma unroll
    for (int i = 0; i < 4; ++i) {
        int r = r0 + rg*4 + i;
        if (r < R)
            *reinterpret_cast<float4*>(&out[(size_t)r*FDIM + cg*4]) =
                make_float4(acc[i][0], acc[i][1], acc[i][2], acc[i][3]);
    }
}

// ---------------------------------------------------------------- fused edge layer
// Per 64-edge chunk:
//   de/dir from disp; msg = (de@meW^T)*mnp[e0]*mnp[e1]; atom[e0] += msg;
//   a1 = silu(msg@W11^T)@W12^T; fnew[e0] += a1*dir
//   a2 = silu(msg@W21^T)@W22^T; fnew[e0] += a2*fold[e1]
__global__ __launch_bounds__(TPB)
void edge_layer_kernel(const float* __restrict__ disp,
                       const int* __restrict__ ei0, const int* __restrict__ ei1,
                       const float* __restrict__ mnp,
                       const float* __restrict__ meW,
                       const float* __restrict__ W11, const float* __restrict__ W12,
                       const float* __restrict__ W21, const float* __restrict__ W22,
                       const float* __restrict__ fold,
                       float* __restrict__ atom,
                       float* __restrict__ fnew,
                       int E)
{
    __shared__ float Wt[FDIM][WPAD];       // 66.0 KB
    __shared__ float A[CHUNK][FDIM];       // 32 KB  (msg, persists both passes)
    __shared__ float H[CHUNK][FDIM];       // 32 KB  (hidden / MLP output)
    __shared__ float meWs[FDIM][21];       // 10.5 KB (pad 21: 2-way max on reads)
    __shared__ float de[CHUNK][NBASIS];    // 5 KB
    __shared__ float dirc[CHUNK][3];
    __shared__ int   e0c[CHUNK];
    __shared__ int   e1c[CHUNK];

    const int tid = threadIdx.x;
    const int r0  = blockIdx.x * CHUNK;
    const int rg  = tid >> 5, cg = tid & 31;
    const int nvalid = min(CHUNK, E - r0);

    // stage radial-weight matrix [f][b]
    for (int p = tid; p < FDIM*NBASIS; p += TPB)
        meWs[p / NBASIS][p % NBASIS] = meW[p];

    // per-edge embedding (1 wave does real work; cheap vs 4 GEMMs)
    if (tid < CHUNK) {
        int r = tid;
        float x = 0.f, y = 0.f, zz = 0.f;
        int a0 = 0, a1i = 0;
        if (r < nvalid) {
            a0  = ei0[r0 + r];
            a1i = ei1[r0 + r];
            const float* dp = disp + 3*(size_t)(r0 + r);
            x = dp[0]; y = dp[1]; zz = dp[2];
        }
        e0c[r] = a0; e1c[r] = a1i;
        float d   = sqrtf(x*x + y*y + zz*zz);
        float inv = (r < nvalid) ? 1.0f/d : 0.f;
        dirc[r][0] = x*inv; dirc[r][1] = y*inv; dirc[r][2] = zz*inv;
        float cut = (d < RCUT) ? 0.5f*(cosf(PI_F*d/RCUT) + 1.f) : 0.f;
        float s   = sqrtf(2.f/RCUT) * cut * inv;
        float w   = PI_F * d / RCUT;
        #pragma unroll
        for (int b = 0; b < NBASIS; ++b)
            de[r][b] = s * sinf((float)(b+1) * w);
    }
    stage_wt(W11, Wt, tid);   // overlap: Wt disjoint from above
    __syncthreads();

    // msg into A + atomic scatter into atom
    #pragma unroll
    for (int i = 0; i < (CHUNK*FDIM)/TPB; ++i) {
        int idx = tid + i*TPB;
        int r = idx >> 7, f = idx & 127;
        float mep = 0.f;
        #pragma unroll
        for (int b = 0; b < NBASIS; ++b) mep += de[r][b] * meWs[f][b];
        float m = 0.f;
        if (r < nvalid) {
            m = mep * mnp[(size_t)e0c[r]*FDIM + f] * mnp[(size_t)e1c[r]*FDIM + f];
            atomicAdd(&atom[(size_t)e0c[r]*FDIM + f], m);
        }
        A[r][f] = m;
    }
    __syncthreads();   // A ready, W11 ready

    for (int pass = 0; pass < 2; ++pass) {
        if (pass) {                       // W11 staged pre-msg for pass 0
            stage_wt(W21, Wt, tid);
            __syncthreads();
        }
        float acc[4][4];
        #pragma unroll
        for (int i = 0; i < 4; ++i)
            { acc[i][0]=0.f; acc[i][1]=0.f; acc[i][2]=0.f; acc[i][3]=0.f; }
        gemm64(A, Wt, rg, cg, acc);       // reads A, Wt
        #pragma unroll
        for (int i = 0; i < 4; ++i) {
            float4 hv;
            hv.x = silu_f(acc[i][0]); hv.y = silu_f(acc[i][1]);
            hv.z = silu_f(acc[i][2]); hv.w = silu_f(acc[i][3]);
            *reinterpret_cast<float4*>(&H[rg*4+i][cg*4]) = hv;
        }
        __syncthreads();                  // Wt reads done + H written

        stage_wt(pass ? W22 : W12, Wt, tid);
        __syncthreads();

        #pragma unroll
        for (int i = 0; i < 4; ++i)
            { acc[i][0]=0.f; acc[i][1]=0.f; acc[i][2]=0.f; acc[i][3]=0.f; }
        gemm64(H, Wt, rg, cg, acc);
        __syncthreads();                  // H reads done before overwrite
        #pragma unroll
        for (int i = 0; i < 4; ++i)
            *reinterpret_cast<float4*>(&H[rg*4+i][cg*4]) =
                make_float4(acc[i][0], acc[i][1], acc[i][2], acc[i][3]);
        __syncthreads();                  // H = MLP output

        // scatter: fnew[e0] += H * (pass0: dir | pass1: fold[e1]); f-coalesced atomics
        if (pass == 0) {
            #pragma unroll
            for (int v = 0; v < 3; ++v) {
                #pragma unroll
                for (int j = 0; j < (CHUNK*FDIM)/TPB; ++j) {
                    int idx = tid + j*TPB;
                    int r = idx >> 7, f = idx & 127;
                    if (r < nvalid)
                        atomicAdd(&fnew[(size_t)e0c[r]*3*FDIM + v*FDIM + f],
                                  H[r][f] * dirc[r][v]);
                }
            }
        } else {
            #pragma unroll
            for (int v = 0; v < 3; ++v) {
                #pragma unroll
                for (int j = 0; j < (CHUNK*FDIM)/TPB; ++j) {
                    int idx = tid + j*TPB;
                    int r = idx >> 7, f = idx & 127;
                    if (r < nvalid)
                        atomicAdd(&fnew[(size_t)e0c[r]*3*FDIM + v*FDIM + f],
                                  H[r][f] * fold[(size_t)e1c[r]*3*FDIM + v*FDIM + f]);
                }
            }
        }
        __syncthreads();                  // H reads done before next pass
    }
}

// ---------------------------------------------------------------- node update
// atom[n,g] += sum_v f[n,v,g] * (sum_f f[n,v,f] * W[g,f])
__global__ __launch_bounds__(128)
void upd_kernel(const float* __restrict__ fc, const float* __restrict__ W,
                float* __restrict__ atom)
{
    __shared__ float fl[3][FDIM];
    int n = blockIdx.x, g = threadIdx.x;
    const float* fr = fc + (size_t)n*3*FDIM;
    fl[0][g] = fr[g];
    fl[1][g] = fr[FDIM + g];
    fl[2][g] = fr[2*FDIM + g];
    __syncthreads();
    float t0 = 0.f, t1 = 0.f, t2 = 0.f;
    const float4* wr = reinterpret_cast<const float4*>(W + (size_t)g*FDIM);
    #pragma unroll
    for (int f4 = 0; f4 < FDIM/4; ++f4) {
        float4 w  = wr[f4];
        float4 f0 = *reinterpret_cast<const float4*>(&fl[0][f4*4]);
        float4 f1 = *reinterpret_cast<const float4*>(&fl[1][f4*4]);
        float4 f2 = *reinterpret_cast<const float4*>(&fl[2][f4*4]);
        t0 += w.x*f0.x + w.y*f0.y + w.z*f0.z + w.w*f0.w;
        t1 += w.x*f1.x + w.y*f1.y + w.z*f1.z + w.w*f1.w;
        t2 += w.x*f2.x + w.y*f2.y + w.z*f2.z + w.w*f2.w;
    }
    atom[(size_t)n*FDIM + g] += fl[0][g]*t0 + fl[1][g]*t1 + fl[2][g]*t2;
}

// ---------------------------------------------------------------- launch
extern "C" void kernel_launch(void* const* d_in, const int* in_sizes, int n_in,
                              void* d_out, int out_size, void* d_ws, size_t ws_size,
                              hipStream_t stream)
{
    const int*   zc    = (const int*)d_in[0];
    const float* disp  = (const float*)d_in[1];
    const int*   ei    = (const int*)d_in[2];
    const float* emb   = (const float*)d_in[4];
    const float* mnpW1 = (const float*)d_in[5];
    const float* mnpb1 = (const float*)d_in[6];
    const float* mnpW2 = (const float*)d_in[7];
    const float* mnpb2 = (const float*)d_in[8];
    const float* meW   = (const float*)d_in[9];
    const float* eq1W1 = (const float*)d_in[10];
    const float* eq1W2 = (const float*)d_in[11];
    const float* eq2W1 = (const float*)d_in[12];
    const float* eq2W2 = (const float*)d_in[13];
    const float* updW  = (const float*)d_in[14];

    const int N = in_sizes[0];
    const int E = in_sizes[1] / 3;
    const int* ei0 = ei;
    const int* ei1 = ei + E;

    float* atom = (float*)d_out;                      // [N,F]
    float* fB   = (float*)d_out + (size_t)N * FDIM;   // [N,3,F] (final force)

    float* ws  = (float*)d_ws;                        // total scratch: 41 MB
    float* mnp = ws;  ws += (size_t)N * FDIM;
    float* fA  = ws;  ws += (size_t)N * 3 * FDIM;

    atom_init_kernel<<<(N*FDIM + 255)/256, 256, 0, stream>>>(zc, emb, atom, N);
    hipMemsetAsync(fA, 0, (size_t)N*3*FDIM*sizeof(float), stream);

    for (int l = 0; l < NLAYERS; ++l) {
        const float* fold;  float* fnew;
        if      (l == 0) { fold = fA; fnew = fB; }
        else if (l == 1) { fold = fB; fnew = fA; }
        else             { fold = fA; fnew = fB; }

        node_mlp_kernel<<<(N + CHUNK - 1)/CHUNK, TPB, 0, stream>>>(
            atom, mnp,
            mnpW1 + (size_t)l*FDIM*FDIM, mnpb1 + (size_t)l*FDIM,
            mnpW2 + (size_t)l*FDIM*FDIM, mnpb2 + (size_t)l*FDIM, N);

        if (l == 0) hipMemsetAsync(fnew, 0, (size_t)N*3*FDIM*sizeof(float), stream);
        else        hipMemcpyAsync(fnew, fold, (size_t)N*3*FDIM*sizeof(float),
                                   hipMemcpyDeviceToDevice, stream);

        edge_layer_kernel<<<(E + CHUNK - 1)/CHUNK, TPB, 0, stream>>>(
            disp, ei0, ei1, mnp,
            meW   + (size_t)l*FDIM*NBASIS,
            eq1W1 + (size_t)l*FDIM*FDIM, eq1W2 + (size_t)l*FDIM*FDIM,
            eq2W1 + (size_t)l*FDIM*FDIM, eq2W2 + (size_t)l*FDIM*FDIM,
            fold, atom, fnew, E);

        upd_kernel<<<N, 128, 0, stream>>>(fnew, updW + (size_t)l*FDIM*FDIM, atom);
    }
}

// Round 3
// 4521.796 us; speedup vs baseline: 1.4770x; 1.4770x over previous
//
#include <hip/hip_runtime.h>
#include <cstdint>
#include <cstddef>

#define FDIM   128
#define NBASIS 20
#define NLAYERS 3
#define RCUT   5.0f
#define PI_F   3.14159265358979323846f
#define CHUNK  64
#define TPB    512
#define WPAD   132   // fp32 node-MLP: 528B rows, 16B-aligned

typedef __attribute__((ext_vector_type(8))) short bf16x8;
typedef __attribute__((ext_vector_type(4))) float f32x4;

__device__ __forceinline__ float silu_f(float x) { return x / (1.f + __expf(-x)); }

__device__ __forceinline__ unsigned short f2bf(float x) {  // RNE
    unsigned int u = __float_as_uint(x);
    return (unsigned short)((u + 0x7FFFu + ((u >> 16) & 1u)) >> 16);
}

// swizzled element index for bf16 LDS tiles with 128-elem rows:
// byte ^= (row&7)<<4  <=>  elem ^= (row&7)<<3   (keeps 16B alignment of 8-elem groups)
__device__ __forceinline__ int swz(int row, int col) {
    return row * FDIM + (col ^ ((row & 7) << 3));
}

// ---------------------------------------------------------------- atom init
__global__ __launch_bounds__(256)
void atom_init_kernel(const int* __restrict__ zc, const float* __restrict__ emb,
                      float* __restrict__ atom, int N)
{
    int t = blockIdx.x * 256 + threadIdx.x;
    if (t >= N * FDIM) return;
    int n = t >> 7, f = t & 127;
    atom[t] = emb[zc[n]*FDIM + f];
}

// ================================================================ node MLP (fp32)
// Conflict-free staging: read W k-major (coalesced 256B), write Wt rows.
__device__ __forceinline__ void stage_wt(const float* __restrict__ W,
                                         float (*Wt)[WPAD], int tid)
{
    #pragma unroll
    for (int i = 0; i < 8; ++i) {
        int p = tid + i*TPB;            // 0..4095
        int k = p & 127, c4 = p >> 7;   // c4 0..31
        float4 v;
        v.x = W[(size_t)(c4*4+0)*FDIM + k];
        v.y = W[(size_t)(c4*4+1)*FDIM + k];
        v.z = W[(size_t)(c4*4+2)*FDIM + k];
        v.w = W[(size_t)(c4*4+3)*FDIM + k];
        *reinterpret_cast<float4*>(&Wt[k][c4*4]) = v;   // banks 4k..4k+3: conflict-free
    }
}

__device__ __forceinline__ void gemm64(const float (*src)[FDIM],
                                       const float (*Wt)[WPAD],
                                       int rg, int cg, float acc[4][4])
{
    #pragma unroll
    for (int k4 = 0; k4 < FDIM/4; ++k4) {
        float4 a[4];
        #pragma unroll
        for (int i = 0; i < 4; ++i)
            a[i] = *reinterpret_cast<const float4*>(&src[rg*4+i][k4*4]);
        #pragma unroll
        for (int kk = 0; kk < 4; ++kk) {
            float4 w = *reinterpret_cast<const float4*>(&Wt[k4*4+kk][cg*4]);
            #pragma unroll
            for (int i = 0; i < 4; ++i) {
                float av = (kk==0) ? a[i].x : (kk==1) ? a[i].y : (kk==2) ? a[i].z : a[i].w;
                acc[i][0] += av * w.x;
                acc[i][1] += av * w.y;
                acc[i][2] += av * w.z;
                acc[i][3] += av * w.w;
            }
        }
    }
}

__global__ __launch_bounds__(TPB)
void node_mlp_kernel(const float* __restrict__ in, float* __restrict__ out,
                     const float* __restrict__ W1, const float* __restrict__ b1,
                     const float* __restrict__ W2, const float* __restrict__ b2,
                     int R)
{
    __shared__ float Wt[FDIM][WPAD];
    __shared__ float inb[CHUNK][FDIM];
    __shared__ float hb[CHUNK][FDIM];
    const int tid = threadIdx.x;
    const int r0  = blockIdx.x * CHUNK;
    const int rg  = tid >> 5, cg = tid & 31;

    {
        const float4* gin = reinterpret_cast<const float4*>(in) + (size_t)r0 * (FDIM/4);
        #pragma unroll
        for (int i = 0; i < 4; ++i) {
            int p = tid + i*TPB;
            int r = p >> 5;
            float4 v = make_float4(0.f,0.f,0.f,0.f);
            if (r0 + r < R) v = gin[p];
            *reinterpret_cast<float4*>(&inb[r][(p & 31)*4]) = v;
        }
    }
    stage_wt(W1, Wt, tid);
    __syncthreads();

    float acc[4][4];
    {
        float4 bv = *reinterpret_cast<const float4*>(b1 + cg*4);
        #pragma unroll
        for (int i = 0; i < 4; ++i) {
            acc[i][0]=bv.x; acc[i][1]=bv.y; acc[i][2]=bv.z; acc[i][3]=bv.w;
        }
    }
    gemm64(inb, Wt, rg, cg, acc);
    #pragma unroll
    for (int i = 0; i < 4; ++i) {
        float4 hv;
        hv.x = silu_f(acc[i][0]); hv.y = silu_f(acc[i][1]);
        hv.z = silu_f(acc[i][2]); hv.w = silu_f(acc[i][3]);
        *reinterpret_cast<float4*>(&hb[rg*4+i][cg*4]) = hv;
    }
    __syncthreads();

    stage_wt(W2, Wt, tid);
    __syncthreads();

    {
        float4 bv = *reinterpret_cast<const float4*>(b2 + cg*4);
        #pragma unroll
        for (int i = 0; i < 4; ++i) {
            acc[i][0]=bv.x; acc[i][1]=bv.y; acc[i][2]=bv.z; acc[i][3]=bv.w;
        }
    }
    gemm64(hb, Wt, rg, cg, acc);

    #pragma unroll
    for (int i = 0; i < 4; ++i) {
        int r = r0 + rg*4 + i;
        if (r < R)
            *reinterpret_cast<float4*>(&out[(size_t)r*FDIM + cg*4]) =
                make_float4(acc[i][0], acc[i][1], acc[i][2], acc[i][3]);
    }
}

// ================================================================ fused edge layer (bf16 MFMA)
// Stage fp32 W (row-major [c][k]) -> bf16 swizzled LDS rows.
__device__ __forceinline__ void stage_w_bf16(const float* __restrict__ W,
                                             unsigned short* __restrict__ Wb, int tid)
{
    #pragma unroll
    for (int i = 0; i < 8; ++i) {
        int p = tid + i*TPB;            // 0..4095 float4s
        int c = p >> 5, k4 = p & 31;    // W[c][k4*4..+3], coalesced
        float4 v = reinterpret_cast<const float4*>(W)[p];
        ushort4 o;
        o.x = f2bf(v.x); o.y = f2bf(v.y); o.z = f2bf(v.z); o.w = f2bf(v.w);
        *reinterpret_cast<ushort4*>(&Wb[swz(c, k4*4)]) = o;   // 2-way max
    }
}

// One 64x128 GEMM: D = A(64x128) * W^T(128x128), per-wave 16x64 tile.
// A,W in swizzled bf16 LDS. acc[n] accumulates fragment for cols nc0+n*16.
__device__ __forceinline__ void gemm_mfma(const unsigned short* __restrict__ Asrc,
                                          const unsigned short* __restrict__ Wsrc,
                                          int mr0, int nc0, int lane, f32x4 acc[4])
{
    #pragma unroll
    for (int ks = 0; ks < 4; ++ks) {
        const int arow = mr0 + (lane & 15);
        const int kb   = ks*32 + (lane >> 4)*8;
        bf16x8 a = *reinterpret_cast<const bf16x8*>(&Asrc[swz(arow, kb)]);
        #pragma unroll
        for (int n = 0; n < 4; ++n) {
            const int brow = nc0 + n*16 + (lane & 15);
            bf16x8 b = *reinterpret_cast<const bf16x8*>(&Wsrc[swz(brow, kb)]);
            acc[n] = __builtin_amdgcn_mfma_f32_16x16x32_bf16(a, b, acc[n], 0, 0, 0);
        }
    }
}

__global__ __launch_bounds__(TPB, 4)
void edge_layer_kernel(const float* __restrict__ disp,
                       const int* __restrict__ ei0, const int* __restrict__ ei1,
                       const float* __restrict__ mnp,
                       const float* __restrict__ meW,
                       const float* __restrict__ W11, const float* __restrict__ W12,
                       const float* __restrict__ W21, const float* __restrict__ W22,
                       const float* __restrict__ fold,
                       float* __restrict__ atom,
                       float* __restrict__ fnew,
                       int E)
{
    __shared__ unsigned short Wb[FDIM*FDIM];    // 32 KB (bf16, swizzled)
    __shared__ unsigned short Ab[CHUNK*FDIM];   // 16 KB (msg bf16, swizzled)
    __shared__ unsigned short Hb[CHUNK*FDIM];   // 16 KB (hidden bf16, swizzled)
    __shared__ float de[CHUNK][NBASIS];         // 5 KB
    __shared__ float dirc[CHUNK][3];
    __shared__ int   e0c[CHUNK];
    __shared__ int   e1c[CHUNK];

    const int tid  = threadIdx.x;
    const int lane = tid & 63;
    const int wid  = tid >> 6;                  // 8 waves
    const int r0   = blockIdx.x * CHUNK;
    const int nvalid = min(CHUNK, E - r0);
    const int mr0  = (wid & 3) * 16;            // wave's 16-row slab
    const int nc0  = (wid >> 2) * 64;           // wave's 64-col half

    // ---- P0: edge embedding (wave 0) + stage W11
    if (tid < CHUNK) {
        int r = tid;
        float x = 0.f, y = 0.f, zz = 0.f;
        int a0 = 0, a1i = 0;
        if (r < nvalid) {
            a0  = ei0[r0 + r];
            a1i = ei1[r0 + r];
            const float* dp = disp + 3*(size_t)(r0 + r);
            x = dp[0]; y = dp[1]; zz = dp[2];
        }
        e0c[r] = a0; e1c[r] = a1i;
        float d   = sqrtf(x*x + y*y + zz*zz);
        float inv = (r < nvalid) ? 1.0f/d : 0.f;
        dirc[r][0] = x*inv; dirc[r][1] = y*inv; dirc[r][2] = zz*inv;
        float cut = (d < RCUT) ? 0.5f*(cosf(PI_F*d/RCUT) + 1.f) : 0.f;
        float s   = sqrtf(2.f/RCUT) * cut * inv;
        float w   = PI_F * d / RCUT;
        #pragma unroll
        for (int b = 0; b < NBASIS; ++b)
            de[r][b] = s * sinf((float)(b+1) * w);
    }
    stage_w_bf16(W11, Wb, tid);
    __syncthreads();

    // ---- P1: msg = (de@meW^T)*mnp[e0]*mnp[e1]; atom[e0]+=msg; Ab=bf16(msg)
    {
        const int f = tid & 127;
        float mew[NBASIS];
        #pragma unroll
        for (int b = 0; b < NBASIS; ++b) mew[b] = meW[(size_t)f*NBASIS + b];
        #pragma unroll
        for (int i = 0; i < (CHUNK*FDIM)/TPB; ++i) {   // 16 iters, r = base+4i
            int r = (tid >> 7) + 4*i;
            float mep = 0.f;
            #pragma unroll
            for (int b = 0; b < NBASIS; ++b) mep += de[r][b] * mew[b];
            float m = 0.f;
            if (r < nvalid) {
                m = mep * mnp[(size_t)e0c[r]*FDIM + f] * mnp[(size_t)e1c[r]*FDIM + f];
                atomicAdd(&atom[(size_t)e0c[r]*FDIM + f], m);
            }
            Ab[swz(r, f)] = f2bf(m);
        }
    }
    __syncthreads();

    // ---- two passes: (eq1: *dir) then (eq2: *fold[e1])
    #pragma unroll 1
    for (int pass = 0; pass < 2; ++pass) {
        if (pass) {                     // W11 already staged in P0
            stage_w_bf16(W21, Wb, tid);
            __syncthreads();
        }

        // gemm A: h = silu(msg @ Wx1^T)
        f32x4 acc[4];
        #pragma unroll
        for (int n = 0; n < 4; ++n) acc[n] = (f32x4){0.f,0.f,0.f,0.f};
        gemm_mfma(Ab, Wb, mr0, nc0, lane, acc);
        #pragma unroll
        for (int n = 0; n < 4; ++n)
            #pragma unroll
            for (int q = 0; q < 4; ++q) {
                int row = mr0 + (lane >> 4)*4 + q;
                int col = nc0 + n*16 + (lane & 15);
                Hb[swz(row, col)] = f2bf(silu_f(acc[n][q]));
            }
        __syncthreads();                // Wb reads + Hb writes done

        stage_w_bf16(pass ? W22 : W12, Wb, tid);
        __syncthreads();

        // gemm B: a = h @ Wx2^T, scatter straight from D-fragments
        #pragma unroll
        for (int n = 0; n < 4; ++n) acc[n] = (f32x4){0.f,0.f,0.f,0.f};
        gemm_mfma(Hb, Wb, mr0, nc0, lane, acc);

        if (pass == 0) {
            #pragma unroll
            for (int n = 0; n < 4; ++n)
                #pragma unroll
                for (int q = 0; q < 4; ++q) {
                    int row = mr0 + (lane >> 4)*4 + q;
                    int col = nc0 + n*16 + (lane & 15);
                    if (row < nvalid) {
                        float val = acc[n][q];
                        size_t base = (size_t)e0c[row]*3*FDIM + col;
                        atomicAdd(&fnew[base],          val * dirc[row][0]);
                        atomicAdd(&fnew[base +   FDIM], val * dirc[row][1]);
                        atomicAdd(&fnew[base + 2*FDIM], val * dirc[row][2]);
                    }
                }
        } else {
            #pragma unroll
            for (int n = 0; n < 4; ++n)
                #pragma unroll
                for (int q = 0; q < 4; ++q) {
                    int row = mr0 + (lane >> 4)*4 + q;
                    int col = nc0 + n*16 + (lane & 15);
                    if (row < nvalid) {
                        float val = acc[n][q];
                        size_t gb = (size_t)e1c[row]*3*FDIM + col;
                        size_t base = (size_t)e0c[row]*3*FDIM + col;
                        atomicAdd(&fnew[base],          val * fold[gb]);
                        atomicAdd(&fnew[base +   FDIM], val * fold[gb +   FDIM]);
                        atomicAdd(&fnew[base + 2*FDIM], val * fold[gb + 2*FDIM]);
                    }
                }
        }
        __syncthreads();                // Wb/Hb reads done before next pass restage
    }
}

// ---------------------------------------------------------------- node update
__global__ __launch_bounds__(128)
void upd_kernel(const float* __restrict__ fc, const float* __restrict__ W,
                float* __restrict__ atom)
{
    __shared__ float fl[3][FDIM];
    int n = blockIdx.x, g = threadIdx.x;
    const float* fr = fc + (size_t)n*3*FDIM;
    fl[0][g] = fr[g];
    fl[1][g] = fr[FDIM + g];
    fl[2][g] = fr[2*FDIM + g];
    __syncthreads();
    float t0 = 0.f, t1 = 0.f, t2 = 0.f;
    const float4* wr = reinterpret_cast<const float4*>(W + (size_t)g*FDIM);
    #pragma unroll
    for (int f4 = 0; f4 < FDIM/4; ++f4) {
        float4 w  = wr[f4];
        float4 f0 = *reinterpret_cast<const float4*>(&fl[0][f4*4]);
        float4 f1 = *reinterpret_cast<const float4*>(&fl[1][f4*4]);
        float4 f2 = *reinterpret_cast<const float4*>(&fl[2][f4*4]);
        t0 += w.x*f0.x + w.y*f0.y + w.z*f0.z + w.w*f0.w;
        t1 += w.x*f1.x + w.y*f1.y + w.z*f1.z + w.w*f1.w;
        t2 += w.x*f2.x + w.y*f2.y + w.z*f2.z + w.w*f2.w;
    }
    atom[(size_t)n*FDIM + g] += fl[0][g]*t0 + fl[1][g]*t1 + fl[2][g]*t2;
}

// ---------------------------------------------------------------- launch
extern "C" void kernel_launch(void* const* d_in, const int* in_sizes, int n_in,
                              void* d_out, int out_size, void* d_ws, size_t ws_size,
                              hipStream_t stream)
{
    const int*   zc    = (const int*)d_in[0];
    const float* disp  = (const float*)d_in[1];
    const int*   ei    = (const int*)d_in[2];
    const float* emb   = (const float*)d_in[4];
    const float* mnpW1 = (const float*)d_in[5];
    const float* mnpb1 = (const float*)d_in[6];
    const float* mnpW2 = (const float*)d_in[7];
    const float* mnpb2 = (const float*)d_in[8];
    const float* meW   = (const float*)d_in[9];
    const float* eq1W1 = (const float*)d_in[10];
    const float* eq1W2 = (const float*)d_in[11];
    const float* eq2W1 = (const float*)d_in[12];
    const float* eq2W2 = (const float*)d_in[13];
    const float* updW  = (const float*)d_in[14];

    const int N = in_sizes[0];
    const int E = in_sizes[1] / 3;
    const int* ei0 = ei;
    const int* ei1 = ei + E;

    float* atom = (float*)d_out;                      // [N,F]
    float* fB   = (float*)d_out + (size_t)N * FDIM;   // [N,3,F] (final force)

    float* ws  = (float*)d_ws;                        // scratch: ~41 MB
    float* mnp = ws;  ws += (size_t)N * FDIM;
    float* fA  = ws;  ws += (size_t)N * 3 * FDIM;

    atom_init_kernel<<<(N*FDIM + 255)/256, 256, 0, stream>>>(zc, emb, atom, N);
    hipMemsetAsync(fA, 0, (size_t)N*3*FDIM*sizeof(float), stream);

    for (int l = 0; l < NLAYERS; ++l) {
        const float* fold;  float* fnew;
        if      (l == 0) { fold = fA; fnew = fB; }
        else if (l == 1) { fold = fB; fnew = fA; }
        else             { fold = fA; fnew = fB; }

        node_mlp_kernel<<<(N + CHUNK - 1)/CHUNK, TPB, 0, stream>>>(
            atom, mnp,
            mnpW1 + (size_t)l*FDIM*FDIM, mnpb1 + (size_t)l*FDIM,
            mnpW2 + (size_t)l*FDIM*FDIM, mnpb2 + (size_t)l*FDIM, N);

        if (l == 0) hipMemsetAsync(fnew, 0, (size_t)N*3*FDIM*sizeof(float), stream);
        else        hipMemcpyAsync(fnew, fold, (size_t)N*3*FDIM*sizeof(float),
                                   hipMemcpyDeviceToDevice, stream);

        edge_layer_kernel<<<(E + CHUNK - 1)/CHUNK, TPB, 0, stream>>>(
            disp, ei0, ei1, mnp,
            meW   + (size_t)l*FDIM*NBASIS,
            eq1W1 + (size_t)l*FDIM*FDIM, eq1W2 + (size_t)l*FDIM*FDIM,
            eq2W1 + (size_t)l*FDIM*FDIM, eq2W2 + (size_t)l*FDIM*FDIM,
            fold, atom, fnew, E);

        upd_kernel<<<N, 128, 0, stream>>>(fnew, updW + (size_t)l*FDIM*FDIM, atom);
    }
}

// Round 4
// 3162.052 us; speedup vs baseline: 2.1121x; 1.4300x over previous
//
#include <hip/hip_runtime.h>
#include <cstdint>
#include <cstddef>

#define FDIM   128
#define NBASIS 20
#define NLAYERS 3
#define RCUT   5.0f
#define PI_F   3.14159265358979323846f
#define CHUNK  64
#define TPB    512
#define WPAD   132   // fp32 node-MLP: 528B rows, 16B-aligned

typedef __attribute__((ext_vector_type(8))) short bf16x8;
typedef __attribute__((ext_vector_type(4))) float f32x4;

__device__ __forceinline__ float silu_f(float x) { return x / (1.f + __expf(-x)); }

__device__ __forceinline__ unsigned short f2bf(float x) {  // RNE
    unsigned int u = __float_as_uint(x);
    return (unsigned short)((u + 0x7FFFu + ((u >> 16) & 1u)) >> 16);
}

// swizzled element index for bf16 LDS tiles with 128-elem rows:
// byte ^= (row&7)<<4  <=>  elem ^= (row&7)<<3
__device__ __forceinline__ int swz(int row, int col) {
    return row * FDIM + (col ^ ((row & 7) << 3));
}

// ---------------------------------------------------------------- atom init
__global__ __launch_bounds__(256)
void atom_init_kernel(const int* __restrict__ zc, const float* __restrict__ emb,
                      float* __restrict__ atom, int N)
{
    int t = blockIdx.x * 256 + threadIdx.x;
    if (t >= N * FDIM) return;
    int n = t >> 7, f = t & 127;
    atom[t] = emb[zc[n]*FDIM + f];
}

// ================================================================ node MLP (fp32)
__device__ __forceinline__ void stage_wt(const float* __restrict__ W,
                                         float (*Wt)[WPAD], int tid)
{
    #pragma unroll
    for (int i = 0; i < 8; ++i) {
        int p = tid + i*TPB;            // 0..4095
        int k = p & 127, c4 = p >> 7;   // c4 0..31
        float4 v;
        v.x = W[(size_t)(c4*4+0)*FDIM + k];
        v.y = W[(size_t)(c4*4+1)*FDIM + k];
        v.z = W[(size_t)(c4*4+2)*FDIM + k];
        v.w = W[(size_t)(c4*4+3)*FDIM + k];
        *reinterpret_cast<float4*>(&Wt[k][c4*4]) = v;
    }
}

__device__ __forceinline__ void gemm64(const float (*src)[FDIM],
                                       const float (*Wt)[WPAD],
                                       int rg, int cg, float acc[4][4])
{
    #pragma unroll
    for (int k4 = 0; k4 < FDIM/4; ++k4) {
        float4 a[4];
        #pragma unroll
        for (int i = 0; i < 4; ++i)
            a[i] = *reinterpret_cast<const float4*>(&src[rg*4+i][k4*4]);
        #pragma unroll
        for (int kk = 0; kk < 4; ++kk) {
            float4 w = *reinterpret_cast<const float4*>(&Wt[k4*4+kk][cg*4]);
            #pragma unroll
            for (int i = 0; i < 4; ++i) {
                float av = (kk==0) ? a[i].x : (kk==1) ? a[i].y : (kk==2) ? a[i].z : a[i].w;
                acc[i][0] += av * w.x;
                acc[i][1] += av * w.y;
                acc[i][2] += av * w.z;
                acc[i][3] += av * w.w;
            }
        }
    }
}

__global__ __launch_bounds__(TPB)
void node_mlp_kernel(const float* __restrict__ in, float* __restrict__ out,
                     const float* __restrict__ W1, const float* __restrict__ b1,
                     const float* __restrict__ W2, const float* __restrict__ b2,
                     int R)
{
    __shared__ float Wt[FDIM][WPAD];
    __shared__ float inb[CHUNK][FDIM];
    __shared__ float hb[CHUNK][FDIM];
    const int tid = threadIdx.x;
    const int r0  = blockIdx.x * CHUNK;
    const int rg  = tid >> 5, cg = tid & 31;

    {
        const float4* gin = reinterpret_cast<const float4*>(in) + (size_t)r0 * (FDIM/4);
        #pragma unroll
        for (int i = 0; i < 4; ++i) {
            int p = tid + i*TPB;
            int r = p >> 5;
            float4 v = make_float4(0.f,0.f,0.f,0.f);
            if (r0 + r < R) v = gin[p];
            *reinterpret_cast<float4*>(&inb[r][(p & 31)*4]) = v;
        }
    }
    stage_wt(W1, Wt, tid);
    __syncthreads();

    float acc[4][4];
    {
        float4 bv = *reinterpret_cast<const float4*>(b1 + cg*4);
        #pragma unroll
        for (int i = 0; i < 4; ++i) {
            acc[i][0]=bv.x; acc[i][1]=bv.y; acc[i][2]=bv.z; acc[i][3]=bv.w;
        }
    }
    gemm64(inb, Wt, rg, cg, acc);
    #pragma unroll
    for (int i = 0; i < 4; ++i) {
        float4 hv;
        hv.x = silu_f(acc[i][0]); hv.y = silu_f(acc[i][1]);
        hv.z = silu_f(acc[i][2]); hv.w = silu_f(acc[i][3]);
        *reinterpret_cast<float4*>(&hb[rg*4+i][cg*4]) = hv;
    }
    __syncthreads();

    stage_wt(W2, Wt, tid);
    __syncthreads();

    {
        float4 bv = *reinterpret_cast<const float4*>(b2 + cg*4);
        #pragma unroll
        for (int i = 0; i < 4; ++i) {
            acc[i][0]=bv.x; acc[i][1]=bv.y; acc[i][2]=bv.z; acc[i][3]=bv.w;
        }
    }
    gemm64(hb, Wt, rg, cg, acc);

    #pragma unroll
    for (int i = 0; i < 4; ++i) {
        int r = r0 + rg*4 + i;
        if (r < R)
            *reinterpret_cast<float4*>(&out[(size_t)r*FDIM + cg*4]) =
                make_float4(acc[i][0], acc[i][1], acc[i][2], acc[i][3]);
    }
}

// ================================================================ bf16 MFMA helpers
__device__ __forceinline__ void stage_w_bf16(const float* __restrict__ W,
                                             unsigned short* __restrict__ Wb, int tid)
{
    #pragma unroll
    for (int i = 0; i < 8; ++i) {
        int p = tid + i*TPB;            // 0..4095 float4s
        int c = p >> 5, k4 = p & 31;    // W[c][k4*4..+3], coalesced
        float4 v = reinterpret_cast<const float4*>(W)[p];
        ushort4 o;
        o.x = f2bf(v.x); o.y = f2bf(v.y); o.z = f2bf(v.z); o.w = f2bf(v.w);
        *reinterpret_cast<ushort4*>(&Wb[swz(c, k4*4)]) = o;
    }
}

// D(64x128) = A(64x128) @ W^T; per-wave 16x64 tile; acc[n] = cols nc0+n*16..+15
__device__ __forceinline__ void gemm_mfma(const unsigned short* __restrict__ Asrc,
                                          const unsigned short* __restrict__ Wsrc,
                                          int mr0, int nc0, int lane, f32x4 acc[4])
{
    #pragma unroll
    for (int ks = 0; ks < 4; ++ks) {
        const int arow = mr0 + (lane & 15);
        const int kb   = ks*32 + (lane >> 4)*8;
        bf16x8 a = *reinterpret_cast<const bf16x8*>(&Asrc[swz(arow, kb)]);
        #pragma unroll
        for (int n = 0; n < 4; ++n) {
            const int brow = nc0 + n*16 + (lane & 15);
            bf16x8 b = *reinterpret_cast<const bf16x8*>(&Wsrc[swz(brow, kb)]);
            acc[n] = __builtin_amdgcn_mfma_f32_16x16x32_bf16(a, b, acc[n], 0, 0, 0);
        }
    }
}

// ================================================================ fused edge layer
// Combined scatter: fnew[e0] += a1*dir + a2*fold[e1]  (ONE set of atomics)
__global__ __launch_bounds__(TPB, 4)
void edge_layer_kernel(const float* __restrict__ disp,
                       const int* __restrict__ ei0, const int* __restrict__ ei1,
                       const float* __restrict__ mnp,
                       const float* __restrict__ meW,
                       const float* __restrict__ W11, const float* __restrict__ W12,
                       const float* __restrict__ W21, const float* __restrict__ W22,
                       const float* __restrict__ fold,
                       float* __restrict__ atom,
                       float* __restrict__ fnew,
                       int E)
{
    __shared__ unsigned short Wb[FDIM*FDIM];    // 32 KB
    __shared__ unsigned short Ab[CHUNK*FDIM];   // 16 KB (msg)
    __shared__ unsigned short Hb[CHUNK*FDIM];   // 16 KB (hidden)
    __shared__ float de[CHUNK][NBASIS];
    __shared__ float dirc[CHUNK][3];
    __shared__ int   e0c[CHUNK];
    __shared__ int   e1c[CHUNK];

    const int tid  = threadIdx.x;
    const int lane = tid & 63;
    const int wid  = tid >> 6;
    const int r0   = blockIdx.x * CHUNK;
    const int nvalid = min(CHUNK, E - r0);
    const int mr0  = (wid & 3) * 16;
    const int nc0  = (wid >> 2) * 64;

    // ---- P0: edge embedding + stage W11
    if (tid < CHUNK) {
        int r = tid;
        float x = 0.f, y = 0.f, zz = 0.f;
        int a0 = 0, a1i = 0;
        if (r < nvalid) {
            a0  = ei0[r0 + r];
            a1i = ei1[r0 + r];
            const float* dp = disp + 3*(size_t)(r0 + r);
            x = dp[0]; y = dp[1]; zz = dp[2];
        }
        e0c[r] = a0; e1c[r] = a1i;
        float d   = sqrtf(x*x + y*y + zz*zz);
        float inv = (r < nvalid) ? 1.0f/d : 0.f;
        dirc[r][0] = x*inv; dirc[r][1] = y*inv; dirc[r][2] = zz*inv;
        float cut = (d < RCUT) ? 0.5f*(cosf(PI_F*d/RCUT) + 1.f) : 0.f;
        float s   = sqrtf(2.f/RCUT) * cut * inv;
        float w   = PI_F * d / RCUT;
        #pragma unroll
        for (int b = 0; b < NBASIS; ++b)
            de[r][b] = s * sinf((float)(b+1) * w);
    }
    stage_w_bf16(W11, Wb, tid);
    __syncthreads();

    // ---- P1: msg; atom[e0] += msg; Ab = bf16(msg)
    {
        const int f = tid & 127;
        float mew[NBASIS];
        #pragma unroll
        for (int b = 0; b < NBASIS; ++b) mew[b] = meW[(size_t)f*NBASIS + b];
        #pragma unroll
        for (int i = 0; i < (CHUNK*FDIM)/TPB; ++i) {
            int r = (tid >> 7) + 4*i;
            float mep = 0.f;
            #pragma unroll
            for (int b = 0; b < NBASIS; ++b) mep += de[r][b] * mew[b];
            float m = 0.f;
            if (r < nvalid) {
                m = mep * mnp[(size_t)e0c[r]*FDIM + f] * mnp[(size_t)e1c[r]*FDIM + f];
                atomicAdd(&atom[(size_t)e0c[r]*FDIM + f], m);
            }
            Ab[swz(r, f)] = f2bf(m);
        }
    }
    __syncthreads();

    f32x4 acc[4], va1[4];

    // ---- G1: h1 = silu(msg @ W11^T)
    #pragma unroll
    for (int n = 0; n < 4; ++n) acc[n] = (f32x4){0.f,0.f,0.f,0.f};
    gemm_mfma(Ab, Wb, mr0, nc0, lane, acc);
    #pragma unroll
    for (int n = 0; n < 4; ++n)
        #pragma unroll
        for (int q = 0; q < 4; ++q)
            Hb[swz(mr0 + (lane >> 4)*4 + q, nc0 + n*16 + (lane & 15))] =
                f2bf(silu_f(acc[n][q]));
    __syncthreads();

    stage_w_bf16(W12, Wb, tid);
    __syncthreads();

    // ---- G2: a1 = h1 @ W12^T   (stash in registers)
    #pragma unroll
    for (int n = 0; n < 4; ++n) va1[n] = (f32x4){0.f,0.f,0.f,0.f};
    gemm_mfma(Hb, Wb, mr0, nc0, lane, va1);
    __syncthreads();

    stage_w_bf16(W21, Wb, tid);
    __syncthreads();

    // ---- G3: h2 = silu(msg @ W21^T)
    #pragma unroll
    for (int n = 0; n < 4; ++n) acc[n] = (f32x4){0.f,0.f,0.f,0.f};
    gemm_mfma(Ab, Wb, mr0, nc0, lane, acc);
    #pragma unroll
    for (int n = 0; n < 4; ++n)
        #pragma unroll
        for (int q = 0; q < 4; ++q)
            Hb[swz(mr0 + (lane >> 4)*4 + q, nc0 + n*16 + (lane & 15))] =
                f2bf(silu_f(acc[n][q]));
    __syncthreads();

    stage_w_bf16(W22, Wb, tid);
    __syncthreads();

    // ---- G4: a2 = h2 @ W22^T; combined scatter
    #pragma unroll
    for (int n = 0; n < 4; ++n) acc[n] = (f32x4){0.f,0.f,0.f,0.f};
    gemm_mfma(Hb, Wb, mr0, nc0, lane, acc);

    #pragma unroll
    for (int n = 0; n < 4; ++n)
        #pragma unroll
        for (int q = 0; q < 4; ++q) {
            int row = mr0 + (lane >> 4)*4 + q;
            int col = nc0 + n*16 + (lane & 15);
            if (row < nvalid) {
                float v1 = va1[n][q], v2 = acc[n][q];
                size_t gb   = (size_t)e1c[row]*3*FDIM + col;
                size_t base = (size_t)e0c[row]*3*FDIM + col;
                atomicAdd(&fnew[base],          v1*dirc[row][0] + v2*fold[gb]);
                atomicAdd(&fnew[base +   FDIM], v1*dirc[row][1] + v2*fold[gb +   FDIM]);
                atomicAdd(&fnew[base + 2*FDIM], v1*dirc[row][2] + v2*fold[gb + 2*FDIM]);
            }
        }
}

// ================================================================ node update (MFMA)
// t[r][g] = sum_f fc[r][f] * W[g][f]   (r = n*3+v over R=3N rows)
// atom[n][g] += t[r][g] * fc[r][g]     (atomic sum over v)
__global__ __launch_bounds__(TPB, 4)
void upd_mfma_kernel(const float* __restrict__ fc, const float* __restrict__ W,
                     float* __restrict__ atom, int R)
{
    __shared__ unsigned short Wb[FDIM*FDIM];    // 32 KB
    __shared__ unsigned short Ab[CHUNK*FDIM];   // 16 KB
    const int tid  = threadIdx.x;
    const int lane = tid & 63;
    const int wid  = tid >> 6;
    const int r0   = blockIdx.x * CHUNK;
    const int mr0  = (wid & 3) * 16;
    const int nc0  = (wid >> 2) * 64;

    stage_w_bf16(W, Wb, tid);
    {
        const float4* g = reinterpret_cast<const float4*>(fc) + (size_t)r0 * (FDIM/4);
        #pragma unroll
        for (int i = 0; i < 4; ++i) {
            int p = tid + i*TPB;        // 2048 float4s = 64x128
            int r = p >> 5, c4 = p & 31;
            float4 v = make_float4(0.f,0.f,0.f,0.f);
            if (r0 + r < R) v = g[p];
            ushort4 o;
            o.x = f2bf(v.x); o.y = f2bf(v.y); o.z = f2bf(v.z); o.w = f2bf(v.w);
            *reinterpret_cast<ushort4*>(&Ab[swz(r, c4*4)]) = o;
        }
    }
    __syncthreads();

    f32x4 acc[4];
    #pragma unroll
    for (int n = 0; n < 4; ++n) acc[n] = (f32x4){0.f,0.f,0.f,0.f};
    gemm_mfma(Ab, Wb, mr0, nc0, lane, acc);

    #pragma unroll
    for (int n = 0; n < 4; ++n)
        #pragma unroll
        for (int q = 0; q < 4; ++q) {
            int row  = mr0 + (lane >> 4)*4 + q;
            int col  = nc0 + n*16 + (lane & 15);
            int grow = r0 + row;
            if (grow < R) {
                float fv = fc[(size_t)grow*FDIM + col];
                atomicAdd(&atom[(size_t)(grow/3)*FDIM + col], acc[n][q] * fv);
            }
        }
}

// ---------------------------------------------------------------- launch
extern "C" void kernel_launch(void* const* d_in, const int* in_sizes, int n_in,
                              void* d_out, int out_size, void* d_ws, size_t ws_size,
                              hipStream_t stream)
{
    const int*   zc    = (const int*)d_in[0];
    const float* disp  = (const float*)d_in[1];
    const int*   ei    = (const int*)d_in[2];
    const float* emb   = (const float*)d_in[4];
    const float* mnpW1 = (const float*)d_in[5];
    const float* mnpb1 = (const float*)d_in[6];
    const float* mnpW2 = (const float*)d_in[7];
    const float* mnpb2 = (const float*)d_in[8];
    const float* meW   = (const float*)d_in[9];
    const float* eq1W1 = (const float*)d_in[10];
    const float* eq1W2 = (const float*)d_in[11];
    const float* eq2W1 = (const float*)d_in[12];
    const float* eq2W2 = (const float*)d_in[13];
    const float* updW  = (const float*)d_in[14];

    const int N = in_sizes[0];
    const int E = in_sizes[1] / 3;
    const int* ei0 = ei;
    const int* ei1 = ei + E;

    float* atom = (float*)d_out;                      // [N,F]
    float* fB   = (float*)d_out + (size_t)N * FDIM;   // [N,3,F] (final force)

    float* ws  = (float*)d_ws;                        // scratch: ~41 MB
    float* mnp = ws;  ws += (size_t)N * FDIM;
    float* fA  = ws;  ws += (size_t)N * 3 * FDIM;

    atom_init_kernel<<<(N*FDIM + 255)/256, 256, 0, stream>>>(zc, emb, atom, N);
    hipMemsetAsync(fA, 0, (size_t)N*3*FDIM*sizeof(float), stream);

    for (int l = 0; l < NLAYERS; ++l) {
        const float* fold;  float* fnew;
        if      (l == 0) { fold = fA; fnew = fB; }
        else if (l == 1) { fold = fB; fnew = fA; }
        else             { fold = fA; fnew = fB; }

        node_mlp_kernel<<<(N + CHUNK - 1)/CHUNK, TPB, 0, stream>>>(
            atom, mnp,
            mnpW1 + (size_t)l*FDIM*FDIM, mnpb1 + (size_t)l*FDIM,
            mnpW2 + (size_t)l*FDIM*FDIM, mnpb2 + (size_t)l*FDIM, N);

        if (l == 0) hipMemsetAsync(fnew, 0, (size_t)N*3*FDIM*sizeof(float), stream);
        else        hipMemcpyAsync(fnew, fold, (size_t)N*3*FDIM*sizeof(float),
                                   hipMemcpyDeviceToDevice, stream);

        edge_layer_kernel<<<(E + CHUNK - 1)/CHUNK, TPB, 0, stream>>>(
            disp, ei0, ei1, mnp,
            meW   + (size_t)l*FDIM*NBASIS,
            eq1W1 + (size_t)l*FDIM*FDIM, eq1W2 + (size_t)l*FDIM*FDIM,
            eq2W1 + (size_t)l*FDIM*FDIM, eq2W2 + (size_t)l*FDIM*FDIM,
            fold, atom, fnew, E);

        upd_mfma_kernel<<<(3*N + CHUNK - 1)/CHUNK, TPB, 0, stream>>>(
            fnew, updW + (size_t)l*FDIM*FDIM, atom, 3*N);
    }
}

// Round 5
// 2495.044 us; speedup vs baseline: 2.6767x; 1.2673x over previous
//
#include <hip/hip_runtime.h>
#include <cstdint>
#include <cstddef>

#define FDIM   128
#define NBASIS 20
#define NLAYERS 3
#define RCUT   5.0f
#define PI_F   3.14159265358979323846f
#define CHUNK  64
#define TPB    512
#define WPAD   132   // fp32 node-MLP: 528B rows, 16B-aligned
#define SPAD   132   // fp32 scatter-staging rows (bank-shift 4/row)

typedef __attribute__((ext_vector_type(8))) short bf16x8;
typedef __attribute__((ext_vector_type(4))) float f32x4;

__device__ __forceinline__ float silu_f(float x) { return x / (1.f + __expf(-x)); }

__device__ __forceinline__ unsigned short f2bf(float x) {  // RNE
    unsigned int u = __float_as_uint(x);
    return (unsigned short)((u + 0x7FFFu + ((u >> 16) & 1u)) >> 16);
}

// swizzled element index for bf16 LDS tiles with 128-elem rows
__device__ __forceinline__ int swz(int row, int col) {
    return row * FDIM + (col ^ ((row & 7) << 3));
}

// ---------------------------------------------------------------- small utility kernels
__global__ __launch_bounds__(256)
void atom_init_kernel(const int* __restrict__ zc, const float* __restrict__ emb,
                      float* __restrict__ atom, int N)
{
    int t = blockIdx.x * 256 + threadIdx.x;
    if (t >= N * FDIM) return;
    int n = t >> 7, f = t & 127;
    atom[t] = emb[zc[n]*FDIM + f];
}

__global__ __launch_bounds__(256)
void zero4_kernel(float4* __restrict__ p, int n4)
{
    int t = blockIdx.x * 256 + threadIdx.x;
    if (t < n4) p[t] = make_float4(0.f,0.f,0.f,0.f);
}

__global__ __launch_bounds__(256)
void copy4_kernel(const float4* __restrict__ s, float4* __restrict__ d, int n4)
{
    int t = blockIdx.x * 256 + threadIdx.x;
    if (t < n4) d[t] = s[t];
}

// ---------------------------------------------------------------- edge sort (by ei0)
__global__ __launch_bounds__(256)
void hist_kernel(const int* __restrict__ ei0, int* __restrict__ hist, int E)
{
    int e = blockIdx.x * 256 + threadIdx.x;
    if (e < E) atomicAdd(&hist[ei0[e]], 1);
}

__global__ __launch_bounds__(1024)
void prefix_kernel(const int* __restrict__ hist, int* __restrict__ off, int N, int E)
{
    __shared__ int buf[1024];
    __shared__ int carry;
    const int tid = threadIdx.x;
    if (tid == 0) carry = 0;
    __syncthreads();
    for (int base = 0; base < N; base += 1024) {
        int i = base + tid;
        int v = (i < N) ? hist[i] : 0;
        buf[tid] = v;
        __syncthreads();
        for (int d = 1; d < 1024; d <<= 1) {
            int t = (tid >= d) ? buf[tid - d] : 0;
            __syncthreads();
            buf[tid] += t;
            __syncthreads();
        }
        if (i < N) off[i] = carry + buf[tid] - v;   // exclusive
        __syncthreads();
        if (tid == 0) carry += buf[1023];
        __syncthreads();
    }
}

__global__ __launch_bounds__(256)
void scatter_kernel(const int* __restrict__ ei0, const int* __restrict__ ei1,
                    const float* __restrict__ disp, int* __restrict__ off,
                    int* __restrict__ se0, int* __restrict__ se1,
                    float* __restrict__ sdisp, int E)
{
    int e = blockIdx.x * 256 + threadIdx.x;
    if (e >= E) return;
    int n = ei0[e];
    int pos = atomicAdd(&off[n], 1);
    se0[pos] = n;
    se1[pos] = ei1[e];
    sdisp[3*pos+0] = disp[3*e+0];
    sdisp[3*pos+1] = disp[3*e+1];
    sdisp[3*pos+2] = disp[3*e+2];
}

// ================================================================ node MLP (fp32)
__device__ __forceinline__ void stage_wt(const float* __restrict__ W,
                                         float (*Wt)[WPAD], int tid)
{
    #pragma unroll
    for (int i = 0; i < 8; ++i) {
        int p = tid + i*TPB;
        int k = p & 127, c4 = p >> 7;
        float4 v;
        v.x = W[(size_t)(c4*4+0)*FDIM + k];
        v.y = W[(size_t)(c4*4+1)*FDIM + k];
        v.z = W[(size_t)(c4*4+2)*FDIM + k];
        v.w = W[(size_t)(c4*4+3)*FDIM + k];
        *reinterpret_cast<float4*>(&Wt[k][c4*4]) = v;
    }
}

__device__ __forceinline__ void gemm64(const float (*src)[FDIM],
                                       const float (*Wt)[WPAD],
                                       int rg, int cg, float acc[4][4])
{
    #pragma unroll
    for (int k4 = 0; k4 < FDIM/4; ++k4) {
        float4 a[4];
        #pragma unroll
        for (int i = 0; i < 4; ++i)
            a[i] = *reinterpret_cast<const float4*>(&src[rg*4+i][k4*4]);
        #pragma unroll
        for (int kk = 0; kk < 4; ++kk) {
            float4 w = *reinterpret_cast<const float4*>(&Wt[k4*4+kk][cg*4]);
            #pragma unroll
            for (int i = 0; i < 4; ++i) {
                float av = (kk==0) ? a[i].x : (kk==1) ? a[i].y : (kk==2) ? a[i].z : a[i].w;
                acc[i][0] += av * w.x;
                acc[i][1] += av * w.y;
                acc[i][2] += av * w.z;
                acc[i][3] += av * w.w;
            }
        }
    }
}

__global__ __launch_bounds__(TPB)
void node_mlp_kernel(const float* __restrict__ in, float* __restrict__ out,
                     const float* __restrict__ W1, const float* __restrict__ b1,
                     const float* __restrict__ W2, const float* __restrict__ b2,
                     int R)
{
    __shared__ float Wt[FDIM][WPAD];
    __shared__ float inb[CHUNK][FDIM];
    __shared__ float hb[CHUNK][FDIM];
    const int tid = threadIdx.x;
    const int r0  = blockIdx.x * CHUNK;
    const int rg  = tid >> 5, cg = tid & 31;

    {
        const float4* gin = reinterpret_cast<const float4*>(in) + (size_t)r0 * (FDIM/4);
        #pragma unroll
        for (int i = 0; i < 4; ++i) {
            int p = tid + i*TPB;
            int r = p >> 5;
            float4 v = make_float4(0.f,0.f,0.f,0.f);
            if (r0 + r < R) v = gin[p];
            *reinterpret_cast<float4*>(&inb[r][(p & 31)*4]) = v;
        }
    }
    stage_wt(W1, Wt, tid);
    __syncthreads();

    float acc[4][4];
    {
        float4 bv = *reinterpret_cast<const float4*>(b1 + cg*4);
        #pragma unroll
        for (int i = 0; i < 4; ++i) {
            acc[i][0]=bv.x; acc[i][1]=bv.y; acc[i][2]=bv.z; acc[i][3]=bv.w;
        }
    }
    gemm64(inb, Wt, rg, cg, acc);
    #pragma unroll
    for (int i = 0; i < 4; ++i) {
        float4 hv;
        hv.x = silu_f(acc[i][0]); hv.y = silu_f(acc[i][1]);
        hv.z = silu_f(acc[i][2]); hv.w = silu_f(acc[i][3]);
        *reinterpret_cast<float4*>(&hb[rg*4+i][cg*4]) = hv;
    }
    __syncthreads();

    stage_wt(W2, Wt, tid);
    __syncthreads();

    {
        float4 bv = *reinterpret_cast<const float4*>(b2 + cg*4);
        #pragma unroll
        for (int i = 0; i < 4; ++i) {
            acc[i][0]=bv.x; acc[i][1]=bv.y; acc[i][2]=bv.z; acc[i][3]=bv.w;
        }
    }
    gemm64(hb, Wt, rg, cg, acc);

    #pragma unroll
    for (int i = 0; i < 4; ++i) {
        int r = r0 + rg*4 + i;
        if (r < R)
            *reinterpret_cast<float4*>(&out[(size_t)r*FDIM + cg*4]) =
                make_float4(acc[i][0], acc[i][1], acc[i][2], acc[i][3]);
    }
}

// ================================================================ bf16 MFMA helpers
__device__ __forceinline__ void stage_w_bf16(const float* __restrict__ W,
                                             unsigned short* __restrict__ Wb, int tid)
{
    #pragma unroll
    for (int i = 0; i < 8; ++i) {
        int p = tid + i*TPB;
        int c = p >> 5, k4 = p & 31;
        float4 v = reinterpret_cast<const float4*>(W)[p];
        ushort4 o;
        o.x = f2bf(v.x); o.y = f2bf(v.y); o.z = f2bf(v.z); o.w = f2bf(v.w);
        *reinterpret_cast<ushort4*>(&Wb[swz(c, k4*4)]) = o;
    }
}

__device__ __forceinline__ void gemm_mfma(const unsigned short* __restrict__ Asrc,
                                          const unsigned short* __restrict__ Wsrc,
                                          int mr0, int nc0, int lane, f32x4 acc[4])
{
    #pragma unroll
    for (int ks = 0; ks < 4; ++ks) {
        const int arow = mr0 + (lane & 15);
        const int kb   = ks*32 + (lane >> 4)*8;
        bf16x8 a = *reinterpret_cast<const bf16x8*>(&Asrc[swz(arow, kb)]);
        #pragma unroll
        for (int n = 0; n < 4; ++n) {
            const int brow = nc0 + n*16 + (lane & 15);
            bf16x8 b = *reinterpret_cast<const bf16x8*>(&Wsrc[swz(brow, kb)]);
            acc[n] = __builtin_amdgcn_mfma_f32_16x16x32_bf16(a, b, acc[n], 0, 0, 0);
        }
    }
}

// ================================================================ fused edge layer (sorted edges)
__global__ __launch_bounds__(TPB, 4)
void edge_layer_kernel(const float* __restrict__ sdisp,
                       const int* __restrict__ se0, const int* __restrict__ se1,
                       const float* __restrict__ mnp,
                       const float* __restrict__ meW,
                       const float* __restrict__ W11, const float* __restrict__ W12,
                       const float* __restrict__ W21, const float* __restrict__ W22,
                       const float* __restrict__ fold,
                       float* __restrict__ atom,
                       float* __restrict__ fnew,
                       int E)
{
    __shared__ unsigned short Wb[FDIM*FDIM];            // 32 KB
    __shared__ union {
        struct { unsigned short Ab[CHUNK*FDIM]; unsigned short Hb[CHUNK*FDIM]; } g;
        float S[CHUNK][SPAD];                           // 33.8 KB (scatter staging)
    } U;
    __shared__ float de[CHUNK][NBASIS];
    __shared__ float dirc[CHUNK][3];
    __shared__ int   e0c[CHUNK], e1c[CHUNK];
    __shared__ int   segrow[CHUNK];
    __shared__ int   nseg_sh;

    const int tid  = threadIdx.x;
    const int lane = tid & 63;
    const int wid  = tid >> 6;
    const int r0   = blockIdx.x * CHUNK;
    const int nvalid = min(CHUNK, E - r0);
    const int mr0  = (wid & 3) * 16;
    const int nc0  = (wid >> 2) * 64;

    // ---- P0: edge embedding + segment list (wave 0) + stage W11
    if (tid < CHUNK) {
        int r = tid;
        int gidx  = r0 + min(r, nvalid - 1);
        int gprev = r0 + min(r - 1, nvalid - 1);
        int e0v = se0[gidx];
        bool head = (r == 0) || (r < nvalid && se0[gprev] != e0v);
        e0c[r] = e0v;
        int a1i = 0;
        float x = 0.f, y = 0.f, zz = 0.f;
        if (r < nvalid) {
            a1i = se1[r0 + r];
            const float* dp = sdisp + 3*(size_t)(r0 + r);
            x = dp[0]; y = dp[1]; zz = dp[2];
        }
        e1c[r] = a1i;
        float d   = sqrtf(x*x + y*y + zz*zz);
        float inv = (r < nvalid) ? 1.0f/d : 0.f;
        dirc[r][0] = x*inv; dirc[r][1] = y*inv; dirc[r][2] = zz*inv;
        float cut = (d < RCUT) ? 0.5f*(cosf(PI_F*d/RCUT) + 1.f) : 0.f;
        float s   = sqrtf(2.f/RCUT) * cut * inv;
        float w   = PI_F * d / RCUT;
        #pragma unroll
        for (int b = 0; b < NBASIS; ++b)
            de[r][b] = s * sinf((float)(b+1) * w);
        unsigned long long mask = __ballot(head);
        int sid = __popcll(mask & ((1ULL << r) - 1ULL));
        if (head) segrow[sid] = r;
        if (r == 0) nseg_sh = (int)__popcll(mask);
    }
    stage_w_bf16(W11, Wb, tid);
    __syncthreads();

    // ---- P1: msg; segment-flushed atom scatter; Ab = bf16(msg)
    {
        const int f  = tid & 127;
        const int q4 = tid >> 7;                 // rows q4*16 .. +15 (consecutive!)
        float mew[NBASIS];
        #pragma unroll
        for (int b = 0; b < NBASIS; ++b) mew[b] = meW[(size_t)f*NBASIS + b];
        int   prev = e0c[q4*16];
        float mv0  = mnp[(size_t)prev*FDIM + f];
        float macc = 0.f;
        #pragma unroll
        for (int i = 0; i < 16; ++i) {
            int r = q4*16 + i;
            int e0 = e0c[r];
            if (e0 != prev) {
                atomicAdd(&atom[(size_t)prev*FDIM + f], macc);
                macc = 0.f; prev = e0;
                mv0 = mnp[(size_t)e0*FDIM + f];
            }
            float m = 0.f;
            if (r < nvalid) {
                float mep = 0.f;
                #pragma unroll
                for (int b = 0; b < NBASIS; ++b) mep += de[r][b] * mew[b];
                m = mep * mv0 * mnp[(size_t)e1c[r]*FDIM + f];
                macc += m;
            }
            U.g.Ab[swz(r, f)] = f2bf(m);
        }
        atomicAdd(&atom[(size_t)prev*FDIM + f], macc);
    }
    __syncthreads();

    f32x4 va1[4], vacc[4];

    // ---- G1: h1 = silu(msg @ W11^T)
    #pragma unroll
    for (int n = 0; n < 4; ++n) vacc[n] = (f32x4){0.f,0.f,0.f,0.f};
    gemm_mfma(U.g.Ab, Wb, mr0, nc0, lane, vacc);
    #pragma unroll
    for (int n = 0; n < 4; ++n)
        #pragma unroll
        for (int q = 0; q < 4; ++q)
            U.g.Hb[swz(mr0 + (lane >> 4)*4 + q, nc0 + n*16 + (lane & 15))] =
                f2bf(silu_f(vacc[n][q]));
    __syncthreads();

    stage_w_bf16(W12, Wb, tid);
    __syncthreads();

    // ---- G2: a1 = h1 @ W12^T   (keep in registers)
    #pragma unroll
    for (int n = 0; n < 4; ++n) va1[n] = (f32x4){0.f,0.f,0.f,0.f};
    gemm_mfma(U.g.Hb, Wb, mr0, nc0, lane, va1);
    __syncthreads();

    stage_w_bf16(W21, Wb, tid);
    __syncthreads();

    // ---- G3: h2 = silu(msg @ W21^T)
    #pragma unroll
    for (int n = 0; n < 4; ++n) vacc[n] = (f32x4){0.f,0.f,0.f,0.f};
    gemm_mfma(U.g.Ab, Wb, mr0, nc0, lane, vacc);
    __syncthreads();                          // Ab reads done; Hb safe to rewrite
    #pragma unroll
    for (int n = 0; n < 4; ++n)
        #pragma unroll
        for (int q = 0; q < 4; ++q)
            U.g.Hb[swz(mr0 + (lane >> 4)*4 + q, nc0 + n*16 + (lane & 15))] =
                f2bf(silu_f(vacc[n][q]));
    __syncthreads();

    stage_w_bf16(W22, Wb, tid);
    __syncthreads();

    // ---- G4: a2 = h2 @ W22^T
    #pragma unroll
    for (int n = 0; n < 4; ++n) vacc[n] = (f32x4){0.f,0.f,0.f,0.f};
    gemm_mfma(U.g.Hb, Wb, mr0, nc0, lane, vacc);
    __syncthreads();                          // all U.g reads done -> U.S may overwrite

    // ---- scatter: fnew[e0] += a1*dir + a2*fold[e1], segment-reduced per v
    const int nseg = nseg_sh;
    for (int v = 0; v < 3; ++v) {
        #pragma unroll
        for (int n = 0; n < 4; ++n)
            #pragma unroll
            for (int q = 0; q < 4; ++q) {
                int row = mr0 + (lane >> 4)*4 + q;
                int col = nc0 + n*16 + (lane & 15);
                float fv = fold[(size_t)e1c[row]*3*FDIM + v*FDIM + col];
                U.S[row][col] = va1[n][q]*dirc[row][v] + vacc[n][q]*fv;
            }
        __syncthreads();
        {
            int col = tid & 127;
            for (int s = tid >> 7; s < nseg; s += 4) {
                int rb = segrow[s];
                int re = (s + 1 < nseg) ? segrow[s+1] : CHUNK;
                float sum = 0.f;
                for (int r = rb; r < re; ++r) sum += U.S[r][col];
                atomicAdd(&fnew[(size_t)e0c[rb]*3*FDIM + v*FDIM + col], sum);
            }
        }
        __syncthreads();
    }
}

// ================================================================ node update (MFMA)
__global__ __launch_bounds__(TPB, 4)
void upd_mfma_kernel(const float* __restrict__ fc, const float* __restrict__ W,
                     float* __restrict__ atom, int R)
{
    __shared__ unsigned short Wb[FDIM*FDIM];
    __shared__ unsigned short Ab[CHUNK*FDIM];
    const int tid  = threadIdx.x;
    const int lane = tid & 63;
    const int wid  = tid >> 6;
    const int r0   = blockIdx.x * CHUNK;
    const int mr0  = (wid & 3) * 16;
    const int nc0  = (wid >> 2) * 64;

    stage_w_bf16(W, Wb, tid);
    {
        const float4* g = reinterpret_cast<const float4*>(fc) + (size_t)r0 * (FDIM/4);
        #pragma unroll
        for (int i = 0; i < 4; ++i) {
            int p = tid + i*TPB;
            int r = p >> 5, c4 = p & 31;
            float4 v = make_float4(0.f,0.f,0.f,0.f);
            if (r0 + r < R) v = g[p];
            ushort4 o;
            o.x = f2bf(v.x); o.y = f2bf(v.y); o.z = f2bf(v.z); o.w = f2bf(v.w);
            *reinterpret_cast<ushort4*>(&Ab[swz(r, c4*4)]) = o;
        }
    }
    __syncthreads();

    f32x4 acc[4];
    #pragma unroll
    for (int n = 0; n < 4; ++n) acc[n] = (f32x4){0.f,0.f,0.f,0.f};
    gemm_mfma(Ab, Wb, mr0, nc0, lane, acc);

    #pragma unroll
    for (int n = 0; n < 4; ++n)
        #pragma unroll
        for (int q = 0; q < 4; ++q) {
            int row  = mr0 + (lane >> 4)*4 + q;
            int col  = nc0 + n*16 + (lane & 15);
            int grow = r0 + row;
            if (grow < R) {
                float fv = fc[(size_t)grow*FDIM + col];
                atomicAdd(&atom[(size_t)(grow/3)*FDIM + col], acc[n][q] * fv);
            }
        }
}

// ---------------------------------------------------------------- launch
extern "C" void kernel_launch(void* const* d_in, const int* in_sizes, int n_in,
                              void* d_out, int out_size, void* d_ws, size_t ws_size,
                              hipStream_t stream)
{
    const int*   zc    = (const int*)d_in[0];
    const float* disp  = (const float*)d_in[1];
    const int*   ei    = (const int*)d_in[2];
    const float* emb   = (const float*)d_in[4];
    const float* mnpW1 = (const float*)d_in[5];
    const float* mnpb1 = (const float*)d_in[6];
    const float* mnpW2 = (const float*)d_in[7];
    const float* mnpb2 = (const float*)d_in[8];
    const float* meW   = (const float*)d_in[9];
    const float* eq1W1 = (const float*)d_in[10];
    const float* eq1W2 = (const float*)d_in[11];
    const float* eq2W1 = (const float*)d_in[12];
    const float* eq2W2 = (const float*)d_in[13];
    const float* updW  = (const float*)d_in[14];

    const int N = in_sizes[0];
    const int E = in_sizes[1] / 3;
    const int* ei0 = ei;
    const int* ei1 = ei + E;

    float* atom = (float*)d_out;                      // [N,F]
    float* fB   = (float*)d_out + (size_t)N * FDIM;   // [N,3,F] (final force)

    float* ws   = (float*)d_ws;                       // ~50 MB total
    float* mnp   = ws;  ws += (size_t)N * FDIM;
    float* fA    = ws;  ws += (size_t)N * 3 * FDIM;
    float* sdisp = ws;  ws += (size_t)E * 3;
    int*   hist  = (int*)ws;
    int*   off   = hist + N;
    int*   se0   = off + N + 1;
    int*   se1   = se0 + E;

    const int n4F  = N * FDIM / 4;            // float4 count for [N,F]
    const int n4F3 = N * 3 * FDIM / 4;        // float4 count for [N,3,F]
    const int eb   = (E + 255) / 256;

    // sort edges by destination (once per call)
    hipMemsetAsync(hist, 0, (size_t)N * sizeof(int), stream);
    hist_kernel<<<eb, 256, 0, stream>>>(ei0, hist, E);
    prefix_kernel<<<1, 1024, 0, stream>>>(hist, off, N, E);
    scatter_kernel<<<eb, 256, 0, stream>>>(ei0, ei1, disp, off, se0, se1, sdisp, E);

    atom_init_kernel<<<(N*FDIM + 255)/256, 256, 0, stream>>>(zc, emb, atom, N);
    zero4_kernel<<<(n4F3 + 255)/256, 256, 0, stream>>>((float4*)fA, n4F3);

    for (int l = 0; l < NLAYERS; ++l) {
        const float* fold;  float* fnew;
        if      (l == 0) { fold = fA; fnew = fB; }
        else if (l == 1) { fold = fB; fnew = fA; }
        else             { fold = fA; fnew = fB; }

        node_mlp_kernel<<<(N + CHUNK - 1)/CHUNK, TPB, 0, stream>>>(
            atom, mnp,
            mnpW1 + (size_t)l*FDIM*FDIM, mnpb1 + (size_t)l*FDIM,
            mnpW2 + (size_t)l*FDIM*FDIM, mnpb2 + (size_t)l*FDIM, N);

        if (l == 0) zero4_kernel<<<(n4F3 + 255)/256, 256, 0, stream>>>((float4*)fnew, n4F3);
        else        copy4_kernel<<<(n4F3 + 255)/256, 256, 0, stream>>>((const float4*)fold, (float4*)fnew, n4F3);

        edge_layer_kernel<<<(E + CHUNK - 1)/CHUNK, TPB, 0, stream>>>(
            sdisp, se0, se1, mnp,
            meW   + (size_t)l*FDIM*NBASIS,
            eq1W1 + (size_t)l*FDIM*FDIM, eq1W2 + (size_t)l*FDIM*FDIM,
            eq2W1 + (size_t)l*FDIM*FDIM, eq2W2 + (size_t)l*FDIM*FDIM,
            fold, atom, fnew, E);

        upd_mfma_kernel<<<(3*N + CHUNK - 1)/CHUNK, TPB, 0, stream>>>(
            fnew, updW + (size_t)l*FDIM*FDIM, atom, 3*N);
    }
}

// Round 6
// 1199.400 us; speedup vs baseline: 5.5682x; 2.0802x over previous
//
#include <hip/hip_runtime.h>
#include <cstdint>
#include <cstddef>

#define FDIM   128
#define NBASIS 20
#define NLAYERS 3
#define RCUT   5.0f
#define PI_F   3.14159265358979323846f
#define CHUNK  64
#define TPB    512
#define SPAD   132   // fp32 scatter-staging rows (bank-shift 4/row)

typedef __attribute__((ext_vector_type(8))) short bf16x8;
typedef __attribute__((ext_vector_type(4))) float f32x4;

__device__ __forceinline__ float silu_f(float x) { return x / (1.f + __expf(-x)); }

__device__ __forceinline__ unsigned short f2bf(float x) {  // RNE
    unsigned int u = __float_as_uint(x);
    return (unsigned short)((u + 0x7FFFu + ((u >> 16) & 1u)) >> 16);
}

// swizzled element index for bf16 LDS tiles with 128-elem rows
__device__ __forceinline__ int swz(int row, int col) {
    return row * FDIM + (col ^ ((row & 7) << 3));
}

// ---------------------------------------------------------------- small utility kernels
__global__ __launch_bounds__(256)
void atom_init_kernel(const int* __restrict__ zc, const float* __restrict__ emb,
                      float* __restrict__ atom, int N)
{
    int t = blockIdx.x * 256 + threadIdx.x;
    if (t >= N * FDIM) return;
    int n = t >> 7, f = t & 127;
    atom[t] = emb[zc[n]*FDIM + f];
}

__global__ __launch_bounds__(256)
void zero4_kernel(float4* __restrict__ p, int n4)
{
    int t = blockIdx.x * 256 + threadIdx.x;
    if (t < n4) p[t] = make_float4(0.f,0.f,0.f,0.f);
}

__global__ __launch_bounds__(256)
void copy4_kernel(const float4* __restrict__ s, float4* __restrict__ d, int n4)
{
    int t = blockIdx.x * 256 + threadIdx.x;
    if (t < n4) d[t] = s[t];
}

// ---------------------------------------------------------------- edge sort (by ei0)
__global__ __launch_bounds__(256)
void hist_kernel(const int* __restrict__ ei0, int* __restrict__ hist, int E)
{
    int e = blockIdx.x * 256 + threadIdx.x;
    if (e < E) atomicAdd(&hist[ei0[e]], 1);
}

__global__ __launch_bounds__(1024)
void prefix_kernel(const int* __restrict__ hist, int* __restrict__ off, int N, int E)
{
    __shared__ int buf[1024];
    __shared__ int carry;
    const int tid = threadIdx.x;
    if (tid == 0) carry = 0;
    __syncthreads();
    for (int base = 0; base < N; base += 1024) {
        int i = base + tid;
        int v = (i < N) ? hist[i] : 0;
        buf[tid] = v;
        __syncthreads();
        for (int d = 1; d < 1024; d <<= 1) {
            int t = (tid >= d) ? buf[tid - d] : 0;
            __syncthreads();
            buf[tid] += t;
            __syncthreads();
        }
        if (i < N) off[i] = carry + buf[tid] - v;   // exclusive
        __syncthreads();
        if (tid == 0) carry += buf[1023];
        __syncthreads();
    }
}

__global__ __launch_bounds__(256)
void scatter_kernel(const int* __restrict__ ei0, const int* __restrict__ ei1,
                    const float* __restrict__ disp, int* __restrict__ off,
                    int* __restrict__ se0, int* __restrict__ se1,
                    float* __restrict__ sdisp, int E)
{
    int e = blockIdx.x * 256 + threadIdx.x;
    if (e >= E) return;
    int n = ei0[e];
    int pos = atomicAdd(&off[n], 1);
    se0[pos] = n;
    se1[pos] = ei1[e];
    sdisp[3*pos+0] = disp[3*e+0];
    sdisp[3*pos+1] = disp[3*e+1];
    sdisp[3*pos+2] = disp[3*e+2];
}

// ================================================================ bf16 MFMA helpers
__device__ __forceinline__ void stage_w_bf16(const float* __restrict__ W,
                                             unsigned short* __restrict__ Wb, int tid)
{
    #pragma unroll
    for (int i = 0; i < 8; ++i) {
        int p = tid + i*TPB;
        int c = p >> 5, k4 = p & 31;
        float4 v = reinterpret_cast<const float4*>(W)[p];
        ushort4 o;
        o.x = f2bf(v.x); o.y = f2bf(v.y); o.z = f2bf(v.z); o.w = f2bf(v.w);
        *reinterpret_cast<ushort4*>(&Wb[swz(c, k4*4)]) = o;
    }
}

__device__ __forceinline__ void gemm_mfma(const unsigned short* __restrict__ Asrc,
                                          const unsigned short* __restrict__ Wsrc,
                                          int mr0, int nc0, int lane, f32x4 acc[4])
{
    #pragma unroll
    for (int ks = 0; ks < 4; ++ks) {
        const int arow = mr0 + (lane & 15);
        const int kb   = ks*32 + (lane >> 4)*8;
        bf16x8 a = *reinterpret_cast<const bf16x8*>(&Asrc[swz(arow, kb)]);
        #pragma unroll
        for (int n = 0; n < 4; ++n) {
            const int brow = nc0 + n*16 + (lane & 15);
            bf16x8 b = *reinterpret_cast<const bf16x8*>(&Wsrc[swz(brow, kb)]);
            acc[n] = __builtin_amdgcn_mfma_f32_16x16x32_bf16(a, b, acc[n], 0, 0, 0);
        }
    }
}

// ================================================================ node MLP (bf16 MFMA)
// out = silu(in @ W1^T + b1) @ W2^T + b2; biases added to fp32 accumulators.
__global__ __launch_bounds__(TPB, 4)
void node_mlp_mfma_kernel(const float* __restrict__ in, float* __restrict__ out,
                          const float* __restrict__ W1, const float* __restrict__ b1,
                          const float* __restrict__ W2, const float* __restrict__ b2,
                          int R)
{
    __shared__ unsigned short Wb[FDIM*FDIM];    // 32 KB
    __shared__ unsigned short Ab[CHUNK*FDIM];   // 16 KB
    __shared__ unsigned short Hb[CHUNK*FDIM];   // 16 KB
    const int tid  = threadIdx.x;
    const int lane = tid & 63;
    const int wid  = tid >> 6;
    const int r0   = blockIdx.x * CHUNK;
    const int mr0  = (wid & 3) * 16;
    const int nc0  = (wid >> 2) * 64;

    stage_w_bf16(W1, Wb, tid);
    {
        const float4* g = reinterpret_cast<const float4*>(in) + (size_t)r0 * (FDIM/4);
        #pragma unroll
        for (int i = 0; i < 4; ++i) {
            int p = tid + i*TPB;        // 2048 float4s = 64x128
            int r = p >> 5, c4 = p & 31;
            float4 v = make_float4(0.f,0.f,0.f,0.f);
            if (r0 + r < R) v = g[p];
            ushort4 o;
            o.x = f2bf(v.x); o.y = f2bf(v.y); o.z = f2bf(v.z); o.w = f2bf(v.w);
            *reinterpret_cast<ushort4*>(&Ab[swz(r, c4*4)]) = o;
        }
    }
    __syncthreads();

    f32x4 acc[4];

    // G1: h = silu(in @ W1^T + b1)
    #pragma unroll
    for (int n = 0; n < 4; ++n) acc[n] = (f32x4){0.f,0.f,0.f,0.f};
    gemm_mfma(Ab, Wb, mr0, nc0, lane, acc);
    #pragma unroll
    for (int n = 0; n < 4; ++n) {
        int col = nc0 + n*16 + (lane & 15);
        float bv = b1[col];
        #pragma unroll
        for (int q = 0; q < 4; ++q)
            Hb[swz(mr0 + (lane >> 4)*4 + q, col)] = f2bf(silu_f(acc[n][q] + bv));
    }
    __syncthreads();                    // Wb reads done + Hb written

    stage_w_bf16(W2, Wb, tid);
    __syncthreads();

    // G2: out = h @ W2^T + b2
    #pragma unroll
    for (int n = 0; n < 4; ++n) acc[n] = (f32x4){0.f,0.f,0.f,0.f};
    gemm_mfma(Hb, Wb, mr0, nc0, lane, acc);
    #pragma unroll
    for (int n = 0; n < 4; ++n) {
        int col = nc0 + n*16 + (lane & 15);
        float bv = b2[col];
        #pragma unroll
        for (int q = 0; q < 4; ++q) {
            int grow = r0 + mr0 + (lane >> 4)*4 + q;
            if (grow < R) out[(size_t)grow*FDIM + col] = acc[n][q] + bv;
        }
    }
}

// ================================================================ fused edge layer (sorted edges)
__global__ __launch_bounds__(TPB, 4)
void edge_layer_kernel(const float* __restrict__ sdisp,
                       const int* __restrict__ se0, const int* __restrict__ se1,
                       const float* __restrict__ mnp,
                       const float* __restrict__ meW,
                       const float* __restrict__ W11, const float* __restrict__ W12,
                       const float* __restrict__ W21, const float* __restrict__ W22,
                       const float* __restrict__ fold,
                       float* __restrict__ atom,
                       float* __restrict__ fnew,
                       int E)
{
    __shared__ unsigned short Wb[FDIM*FDIM];            // 32 KB
    __shared__ union {
        struct { unsigned short Ab[CHUNK*FDIM]; unsigned short Hb[CHUNK*FDIM]; } g;
        float S[CHUNK][SPAD];                           // 33.8 KB (scatter staging)
    } U;
    __shared__ float de[CHUNK][NBASIS];
    __shared__ float dirc[CHUNK][3];
    __shared__ int   e0c[CHUNK], e1c[CHUNK];
    __shared__ int   segrow[CHUNK];
    __shared__ int   nseg_sh;

    const int tid  = threadIdx.x;
    const int lane = tid & 63;
    const int wid  = tid >> 6;
    const int r0   = blockIdx.x * CHUNK;
    const int nvalid = min(CHUNK, E - r0);
    const int mr0  = (wid & 3) * 16;
    const int nc0  = (wid >> 2) * 64;

    // ---- P0: edge embedding + segment list (wave 0) + stage W11
    if (tid < CHUNK) {
        int r = tid;
        int gidx  = r0 + min(r, nvalid - 1);
        int gprev = r0 + min(r - 1, nvalid - 1);
        int e0v = se0[gidx];
        bool head = (r == 0) || (r < nvalid && se0[gprev] != e0v);
        e0c[r] = e0v;
        int a1i = 0;
        float x = 0.f, y = 0.f, zz = 0.f;
        if (r < nvalid) {
            a1i = se1[r0 + r];
            const float* dp = sdisp + 3*(size_t)(r0 + r);
            x = dp[0]; y = dp[1]; zz = dp[2];
        }
        e1c[r] = a1i;
        float d   = sqrtf(x*x + y*y + zz*zz);
        float inv = (r < nvalid) ? 1.0f/d : 0.f;
        dirc[r][0] = x*inv; dirc[r][1] = y*inv; dirc[r][2] = zz*inv;
        float cut = (d < RCUT) ? 0.5f*(cosf(PI_F*d/RCUT) + 1.f) : 0.f;
        float s   = sqrtf(2.f/RCUT) * cut * inv;
        float w   = PI_F * d / RCUT;
        #pragma unroll
        for (int b = 0; b < NBASIS; ++b)
            de[r][b] = s * sinf((float)(b+1) * w);
        unsigned long long mask = __ballot(head);
        int sid = __popcll(mask & ((1ULL << r) - 1ULL));
        if (head) segrow[sid] = r;
        if (r == 0) nseg_sh = (int)__popcll(mask);
    }
    stage_w_bf16(W11, Wb, tid);
    __syncthreads();

    // ---- P1: msg; segment-flushed atom scatter; Ab = bf16(msg)
    {
        const int f  = tid & 127;
        const int q4 = tid >> 7;                 // rows q4*16 .. +15 (consecutive!)
        float mew[NBASIS];
        #pragma unroll
        for (int b = 0; b < NBASIS; ++b) mew[b] = meW[(size_t)f*NBASIS + b];
        int   prev = e0c[q4*16];
        float mv0  = mnp[(size_t)prev*FDIM + f];
        float macc = 0.f;
        #pragma unroll
        for (int i = 0; i < 16; ++i) {
            int r = q4*16 + i;
            int e0 = e0c[r];
            if (e0 != prev) {
                atomicAdd(&atom[(size_t)prev*FDIM + f], macc);
                macc = 0.f; prev = e0;
                mv0 = mnp[(size_t)e0*FDIM + f];
            }
            float m = 0.f;
            if (r < nvalid) {
                float mep = 0.f;
                #pragma unroll
                for (int b = 0; b < NBASIS; ++b) mep += de[r][b] * mew[b];
                m = mep * mv0 * mnp[(size_t)e1c[r]*FDIM + f];
                macc += m;
            }
            U.g.Ab[swz(r, f)] = f2bf(m);
        }
        atomicAdd(&atom[(size_t)prev*FDIM + f], macc);
    }
    __syncthreads();

    f32x4 va1[4], vacc[4];

    // ---- G1: h1 = silu(msg @ W11^T)
    #pragma unroll
    for (int n = 0; n < 4; ++n) vacc[n] = (f32x4){0.f,0.f,0.f,0.f};
    gemm_mfma(U.g.Ab, Wb, mr0, nc0, lane, vacc);
    #pragma unroll
    for (int n = 0; n < 4; ++n)
        #pragma unroll
        for (int q = 0; q < 4; ++q)
            U.g.Hb[swz(mr0 + (lane >> 4)*4 + q, nc0 + n*16 + (lane & 15))] =
                f2bf(silu_f(vacc[n][q]));
    __syncthreads();

    stage_w_bf16(W12, Wb, tid);
    __syncthreads();

    // ---- G2: a1 = h1 @ W12^T   (keep in registers)
    #pragma unroll
    for (int n = 0; n < 4; ++n) va1[n] = (f32x4){0.f,0.f,0.f,0.f};
    gemm_mfma(U.g.Hb, Wb, mr0, nc0, lane, va1);
    __syncthreads();

    stage_w_bf16(W21, Wb, tid);
    __syncthreads();

    // ---- G3: h2 = silu(msg @ W21^T)
    #pragma unroll
    for (int n = 0; n < 4; ++n) vacc[n] = (f32x4){0.f,0.f,0.f,0.f};
    gemm_mfma(U.g.Ab, Wb, mr0, nc0, lane, vacc);
    __syncthreads();                          // Ab reads done; Hb safe to rewrite
    #pragma unroll
    for (int n = 0; n < 4; ++n)
        #pragma unroll
        for (int q = 0; q < 4; ++q)
            U.g.Hb[swz(mr0 + (lane >> 4)*4 + q, nc0 + n*16 + (lane & 15))] =
                f2bf(silu_f(vacc[n][q]));
    __syncthreads();

    stage_w_bf16(W22, Wb, tid);
    __syncthreads();

    // ---- G4: a2 = h2 @ W22^T
    #pragma unroll
    for (int n = 0; n < 4; ++n) vacc[n] = (f32x4){0.f,0.f,0.f,0.f};
    gemm_mfma(U.g.Hb, Wb, mr0, nc0, lane, vacc);
    __syncthreads();                          // all U.g reads done -> U.S may overwrite

    // ---- scatter: fnew[e0] += a1*dir + a2*fold[e1], segment-reduced per v
    const int nseg = nseg_sh;
    for (int v = 0; v < 3; ++v) {
        #pragma unroll
        for (int n = 0; n < 4; ++n)
            #pragma unroll
            for (int q = 0; q < 4; ++q) {
                int row = mr0 + (lane >> 4)*4 + q;
                int col = nc0 + n*16 + (lane & 15);
                float fv = fold[(size_t)e1c[row]*3*FDIM + v*FDIM + col];
                U.S[row][col] = va1[n][q]*dirc[row][v] + vacc[n][q]*fv;
            }
        __syncthreads();
        {
            int col = tid & 127;
            for (int s = tid >> 7; s < nseg; s += 4) {
                int rb = segrow[s];
                int re = (s + 1 < nseg) ? segrow[s+1] : CHUNK;
                float sum = 0.f;
                for (int r = rb; r < re; ++r) sum += U.S[r][col];
                atomicAdd(&fnew[(size_t)e0c[rb]*3*FDIM + v*FDIM + col], sum);
            }
        }
        __syncthreads();
    }
}

// ================================================================ node update (MFMA)
__global__ __launch_bounds__(TPB, 4)
void upd_mfma_kernel(const float* __restrict__ fc, const float* __restrict__ W,
                     float* __restrict__ atom, int R)
{
    __shared__ unsigned short Wb[FDIM*FDIM];
    __shared__ unsigned short Ab[CHUNK*FDIM];
    const int tid  = threadIdx.x;
    const int lane = tid & 63;
    const int wid  = tid >> 6;
    const int r0   = blockIdx.x * CHUNK;
    const int mr0  = (wid & 3) * 16;
    const int nc0  = (wid >> 2) * 64;

    stage_w_bf16(W, Wb, tid);
    {
        const float4* g = reinterpret_cast<const float4*>(fc) + (size_t)r0 * (FDIM/4);
        #pragma unroll
        for (int i = 0; i < 4; ++i) {
            int p = tid + i*TPB;
            int r = p >> 5, c4 = p & 31;
            float4 v = make_float4(0.f,0.f,0.f,0.f);
            if (r0 + r < R) v = g[p];
            ushort4 o;
            o.x = f2bf(v.x); o.y = f2bf(v.y); o.z = f2bf(v.z); o.w = f2bf(v.w);
            *reinterpret_cast<ushort4*>(&Ab[swz(r, c4*4)]) = o;
        }
    }
    __syncthreads();

    f32x4 acc[4];
    #pragma unroll
    for (int n = 0; n < 4; ++n) acc[n] = (f32x4){0.f,0.f,0.f,0.f};
    gemm_mfma(Ab, Wb, mr0, nc0, lane, acc);

    #pragma unroll
    for (int n = 0; n < 4; ++n)
        #pragma unroll
        for (int q = 0; q < 4; ++q) {
            int row  = mr0 + (lane >> 4)*4 + q;
            int col  = nc0 + n*16 + (lane & 15);
            int grow = r0 + row;
            if (grow < R) {
                float fv = fc[(size_t)grow*FDIM + col];
                atomicAdd(&atom[(size_t)(grow/3)*FDIM + col], acc[n][q] * fv);
            }
        }
}

// ---------------------------------------------------------------- launch
extern "C" void kernel_launch(void* const* d_in, const int* in_sizes, int n_in,
                              void* d_out, int out_size, void* d_ws, size_t ws_size,
                              hipStream_t stream)
{
    const int*   zc    = (const int*)d_in[0];
    const float* disp  = (const float*)d_in[1];
    const int*   ei    = (const int*)d_in[2];
    const float* emb   = (const float*)d_in[4];
    const float* mnpW1 = (const float*)d_in[5];
    const float* mnpb1 = (const float*)d_in[6];
    const float* mnpW2 = (const float*)d_in[7];
    const float* mnpb2 = (const float*)d_in[8];
    const float* meW   = (const float*)d_in[9];
    const float* eq1W1 = (const float*)d_in[10];
    const float* eq1W2 = (const float*)d_in[11];
    const float* eq2W1 = (const float*)d_in[12];
    const float* eq2W2 = (const float*)d_in[13];
    const float* updW  = (const float*)d_in[14];

    const int N = in_sizes[0];
    const int E = in_sizes[1] / 3;
    const int* ei0 = ei;
    const int* ei1 = ei + E;

    float* atom = (float*)d_out;                      // [N,F]
    float* fB   = (float*)d_out + (size_t)N * FDIM;   // [N,3,F] (final force)

    float* ws   = (float*)d_ws;                       // ~50 MB total
    float* mnp   = ws;  ws += (size_t)N * FDIM;
    float* fA    = ws;  ws += (size_t)N * 3 * FDIM;
    float* sdisp = ws;  ws += (size_t)E * 3;
    int*   hist  = (int*)ws;
    int*   off   = hist + N;
    int*   se0   = off + N + 1;
    int*   se1   = se0 + E;

    const int n4F3 = N * 3 * FDIM / 4;        // float4 count for [N,3,F]
    const int eb   = (E + 255) / 256;

    // sort edges by destination (once per call)
    hipMemsetAsync(hist, 0, (size_t)N * sizeof(int), stream);
    hist_kernel<<<eb, 256, 0, stream>>>(ei0, hist, E);
    prefix_kernel<<<1, 1024, 0, stream>>>(hist, off, N, E);
    scatter_kernel<<<eb, 256, 0, stream>>>(ei0, ei1, disp, off, se0, se1, sdisp, E);

    atom_init_kernel<<<(N*FDIM + 255)/256, 256, 0, stream>>>(zc, emb, atom, N);
    zero4_kernel<<<(n4F3 + 255)/256, 256, 0, stream>>>((float4*)fA, n4F3);

    for (int l = 0; l < NLAYERS; ++l) {
        const float* fold;  float* fnew;
        if      (l == 0) { fold = fA; fnew = fB; }
        else if (l == 1) { fold = fB; fnew = fA; }
        else             { fold = fA; fnew = fB; }

        node_mlp_mfma_kernel<<<(N + CHUNK - 1)/CHUNK, TPB, 0, stream>>>(
            atom, mnp,
            mnpW1 + (size_t)l*FDIM*FDIM, mnpb1 + (size_t)l*FDIM,
            mnpW2 + (size_t)l*FDIM*FDIM, mnpb2 + (size_t)l*FDIM, N);

        if (l == 0) zero4_kernel<<<(n4F3 + 255)/256, 256, 0, stream>>>((float4*)fnew, n4F3);
        else        copy4_kernel<<<(n4F3 + 255)/256, 256, 0, stream>>>((const float4*)fold, (float4*)fnew, n4F3);

        edge_layer_kernel<<<(E + CHUNK - 1)/CHUNK, TPB, 0, stream>>>(
            sdisp, se0, se1, mnp,
            meW   + (size_t)l*FDIM*NBASIS,
            eq1W1 + (size_t)l*FDIM*FDIM, eq1W2 + (size_t)l*FDIM*FDIM,
            eq2W1 + (size_t)l*FDIM*FDIM, eq2W2 + (size_t)l*FDIM*FDIM,
            fold, atom, fnew, E);

        upd_mfma_kernel<<<(3*N + CHUNK - 1)/CHUNK, TPB, 0, stream>>>(
            fnew, updW + (size_t)l*FDIM*FDIM, atom, 3*N);
    }
}

// Round 7
// 976.279 us; speedup vs baseline: 6.8408x; 1.2285x over previous
//
#include <hip/hip_runtime.h>
#include <cstdint>
#include <cstddef>

#define FDIM   128
#define NBASIS 20
#define NLAYERS 3
#define RCUT   5.0f
#define PI_F   3.14159265358979323846f
#define CHUNK  64
#define TPB    512

typedef __attribute__((ext_vector_type(8))) short bf16x8;
typedef __attribute__((ext_vector_type(4))) float f32x4;

__device__ __forceinline__ float silu_f(float x) { return x / (1.f + __expf(-x)); }

__device__ __forceinline__ unsigned short f2bf(float x) {  // RNE
    unsigned int u = __float_as_uint(x);
    return (unsigned short)((u + 0x7FFFu + ((u >> 16) & 1u)) >> 16);
}

// swizzled element index for bf16 LDS tiles with 128-elem rows
__device__ __forceinline__ int swz(int row, int col) {
    return row * FDIM + (col ^ ((row & 7) << 3));
}
// fp32 scatter-staging swizzle (4-elem granules)
__device__ __forceinline__ int swz4(int row, int col) {
    return row * FDIM + (col ^ ((row & 7) << 2));
}

// ---------------------------------------------------------------- small utility kernels
__global__ __launch_bounds__(256)
void atom_init_kernel(const int* __restrict__ zc, const float* __restrict__ emb,
                      float* __restrict__ atom, int N)
{
    int t = blockIdx.x * 256 + threadIdx.x;
    if (t >= N * FDIM) return;
    int n = t >> 7, f = t & 127;
    atom[t] = emb[zc[n]*FDIM + f];
}

__global__ __launch_bounds__(256)
void zero4_kernel(float4* __restrict__ p, int n4)
{
    int t = blockIdx.x * 256 + threadIdx.x;
    if (t < n4) p[t] = make_float4(0.f,0.f,0.f,0.f);
}

__global__ __launch_bounds__(256)
void copy4_kernel(const float4* __restrict__ s, float4* __restrict__ d, int n4)
{
    int t = blockIdx.x * 256 + threadIdx.x;
    if (t < n4) d[t] = s[t];
}

// ---------------------------------------------------------------- weight pre-pack
// 21 matrices = 3 layers x {mnpW1,mnpW2,eq1W1,eq1W2,eq2W1,eq2W2,updW}.
// Fragment order: Wpk[m][((r16*4+ks)*64 + lane)*8 + j]
//   = bf16( W[r16*16 + (lane&15)][ks*32 + (lane>>4)*8 + j] )
// -> gemm B-load is one fully-coalesced 16B/lane read.
__global__ __launch_bounds__(256)
void pack_w_kernel(const float* __restrict__ mnpW1, const float* __restrict__ mnpW2,
                   const float* __restrict__ e11,   const float* __restrict__ e12,
                   const float* __restrict__ e21,   const float* __restrict__ e22,
                   const float* __restrict__ updW,
                   unsigned short* __restrict__ wpk)
{
    int t = blockIdx.x * 256 + threadIdx.x;
    if (t >= 21 * 2048) return;
    int m = t >> 11, p = t & 2047;
    int layer = m / 7, kind = m % 7;
    const float* base;
    switch (kind) {
        case 0: base = mnpW1; break;
        case 1: base = mnpW2; break;
        case 2: base = e11;   break;
        case 3: base = e12;   break;
        case 4: base = e21;   break;
        case 5: base = e22;   break;
        default: base = updW; break;
    }
    base += (size_t)layer * FDIM * FDIM;
    int l   = p & 63, fr = p >> 6;          // fr = r16*4+ks
    int r16 = fr >> 2, ks = fr & 3;
    int row = r16*16 + (l & 15);
    int col = ks*32 + (l >> 4)*8;
    const float* src = base + (size_t)row*FDIM + col;
    float4 v0 = *reinterpret_cast<const float4*>(src);
    float4 v1 = *reinterpret_cast<const float4*>(src + 4);
    unsigned short* dst = wpk + (size_t)t * 8;
    ushort4 o0, o1;
    o0.x = f2bf(v0.x); o0.y = f2bf(v0.y); o0.z = f2bf(v0.z); o0.w = f2bf(v0.w);
    o1.x = f2bf(v1.x); o1.y = f2bf(v1.y); o1.z = f2bf(v1.z); o1.w = f2bf(v1.w);
    *reinterpret_cast<ushort4*>(dst)     = o0;
    *reinterpret_cast<ushort4*>(dst + 4) = o1;
}

// ---------------------------------------------------------------- edge sort (by ei0)
__global__ __launch_bounds__(256)
void hist_kernel(const int* __restrict__ ei0, int* __restrict__ hist, int E)
{
    int e = blockIdx.x * 256 + threadIdx.x;
    if (e < E) atomicAdd(&hist[ei0[e]], 1);
}

__global__ __launch_bounds__(1024)
void prefix_kernel(const int* __restrict__ hist, int* __restrict__ off, int N, int E)
{
    __shared__ int buf[1024];
    __shared__ int carry;
    const int tid = threadIdx.x;
    if (tid == 0) carry = 0;
    __syncthreads();
    for (int base = 0; base < N; base += 1024) {
        int i = base + tid;
        int v = (i < N) ? hist[i] : 0;
        buf[tid] = v;
        __syncthreads();
        for (int d = 1; d < 1024; d <<= 1) {
            int t = (tid >= d) ? buf[tid - d] : 0;
            __syncthreads();
            buf[tid] += t;
            __syncthreads();
        }
        if (i < N) off[i] = carry + buf[tid] - v;   // exclusive
        __syncthreads();
        if (tid == 0) carry += buf[1023];
        __syncthreads();
    }
}

__global__ __launch_bounds__(256)
void scatter_kernel(const int* __restrict__ ei0, const int* __restrict__ ei1,
                    const float* __restrict__ disp, int* __restrict__ off,
                    int* __restrict__ se0, int* __restrict__ se1,
                    float* __restrict__ sdisp, int E)
{
    int e = blockIdx.x * 256 + threadIdx.x;
    if (e >= E) return;
    int n = ei0[e];
    int pos = atomicAdd(&off[n], 1);
    se0[pos] = n;
    se1[pos] = ei1[e];
    sdisp[3*pos+0] = disp[3*e+0];
    sdisp[3*pos+1] = disp[3*e+1];
    sdisp[3*pos+2] = disp[3*e+2];
}

// ================================================================ gemm: A from LDS, B from packed global
__device__ __forceinline__ void gemm_g(const unsigned short* __restrict__ Ab,
                                       const unsigned short* __restrict__ Bpk,
                                       int mr0, int nc0, int lane, f32x4 acc[4])
{
    #pragma unroll
    for (int ks = 0; ks < 4; ++ks) {
        bf16x8 a = *reinterpret_cast<const bf16x8*>(
            &Ab[swz(mr0 + (lane & 15), ks*32 + (lane >> 4)*8)]);
        #pragma unroll
        for (int n = 0; n < 4; ++n) {
            int r16 = (nc0 >> 4) + n;
            bf16x8 b = *reinterpret_cast<const bf16x8*>(
                &Bpk[(size_t)(((r16*4 + ks)*64 + lane)) * 8]);
            acc[n] = __builtin_amdgcn_mfma_f32_16x16x32_bf16(a, b, acc[n], 0, 0, 0);
        }
    }
}

// ================================================================ node MLP (bf16 MFMA, global B)
__global__ __launch_bounds__(TPB, 6)
void node_mlp_g_kernel(const float* __restrict__ in, float* __restrict__ out,
                       const unsigned short* __restrict__ W1pk, const float* __restrict__ b1,
                       const unsigned short* __restrict__ W2pk, const float* __restrict__ b2,
                       int R)
{
    __shared__ unsigned short Ab[CHUNK*FDIM];   // 16 KB
    __shared__ unsigned short Hb[CHUNK*FDIM];   // 16 KB
    const int tid  = threadIdx.x;
    const int lane = tid & 63;
    const int wid  = tid >> 6;
    const int r0   = blockIdx.x * CHUNK;
    const int mr0  = (wid & 3) * 16;
    const int nc0  = (wid >> 2) * 64;

    {
        const float4* g = reinterpret_cast<const float4*>(in) + (size_t)r0 * (FDIM/4);
        #pragma unroll
        for (int i = 0; i < 4; ++i) {
            int p = tid + i*TPB;
            int r = p >> 5, c4 = p & 31;
            float4 v = make_float4(0.f,0.f,0.f,0.f);
            if (r0 + r < R) v = g[p];
            ushort4 o;
            o.x = f2bf(v.x); o.y = f2bf(v.y); o.z = f2bf(v.z); o.w = f2bf(v.w);
            *reinterpret_cast<ushort4*>(&Ab[swz(r, c4*4)]) = o;
        }
    }
    __syncthreads();

    f32x4 acc[4];
    #pragma unroll
    for (int n = 0; n < 4; ++n) acc[n] = (f32x4){0.f,0.f,0.f,0.f};
    gemm_g(Ab, W1pk, mr0, nc0, lane, acc);
    #pragma unroll
    for (int n = 0; n < 4; ++n) {
        int col = nc0 + n*16 + (lane & 15);
        float bv = b1[col];
        #pragma unroll
        for (int q = 0; q < 4; ++q)
            Hb[swz(mr0 + (lane >> 4)*4 + q, col)] = f2bf(silu_f(acc[n][q] + bv));
    }
    __syncthreads();

    #pragma unroll
    for (int n = 0; n < 4; ++n) acc[n] = (f32x4){0.f,0.f,0.f,0.f};
    gemm_g(Hb, W2pk, mr0, nc0, lane, acc);
    #pragma unroll
    for (int n = 0; n < 4; ++n) {
        int col = nc0 + n*16 + (lane & 15);
        float bv = b2[col];
        #pragma unroll
        for (int q = 0; q < 4; ++q) {
            int grow = r0 + mr0 + (lane >> 4)*4 + q;
            if (grow < R) out[(size_t)grow*FDIM + col] = acc[n][q] + bv;
        }
    }
}

// ================================================================ fused edge layer (sorted edges, global B)
__global__ __launch_bounds__(TPB, 6)
void edge_layer_kernel(const float* __restrict__ sdisp,
                       const int* __restrict__ se0, const int* __restrict__ se1,
                       const float* __restrict__ mnp,
                       const float* __restrict__ meW,
                       const unsigned short* __restrict__ W11pk,
                       const unsigned short* __restrict__ W12pk,
                       const unsigned short* __restrict__ W21pk,
                       const unsigned short* __restrict__ W22pk,
                       const float* __restrict__ fold,
                       float* __restrict__ atom,
                       float* __restrict__ fnew,
                       int E)
{
    __shared__ union {
        struct { unsigned short Ab[CHUNK*FDIM]; unsigned short Hb0[CHUNK*FDIM]; } g;
        float S[CHUNK*FDIM];                    // 32 KB scatter staging (swz4)
    } U;
    __shared__ union {
        unsigned short Hb1[CHUNK*FDIM];         // 16 KB (written in G3, after de is dead)
        float de[CHUNK][NBASIS];                // 5 KB  (read only in P1)
    } V;
    __shared__ float dirc[CHUNK][3];
    __shared__ int   e0c[CHUNK], e1c[CHUNK];
    __shared__ int   segrow[CHUNK];
    __shared__ int   nseg_sh;

    const int tid  = threadIdx.x;
    const int lane = tid & 63;
    const int wid  = tid >> 6;
    const int r0   = blockIdx.x * CHUNK;
    const int nvalid = min(CHUNK, E - r0);
    const int mr0  = (wid & 3) * 16;
    const int nc0  = (wid >> 2) * 64;

    // ---- P0: edge embedding + segment list (wave 0)
    if (tid < CHUNK) {
        int r = tid;
        int gidx  = r0 + min(r, nvalid - 1);
        int gprev = r0 + min(r - 1, nvalid - 1);
        int e0v = se0[gidx];
        bool head = (r == 0) || (r < nvalid && se0[gprev] != e0v);
        e0c[r] = e0v;
        int a1i = 0;
        float x = 0.f, y = 0.f, zz = 0.f;
        if (r < nvalid) {
            a1i = se1[r0 + r];
            const float* dp = sdisp + 3*(size_t)(r0 + r);
            x = dp[0]; y = dp[1]; zz = dp[2];
        }
        e1c[r] = a1i;
        float d   = sqrtf(x*x + y*y + zz*zz);
        float inv = (r < nvalid) ? 1.0f/d : 0.f;
        dirc[r][0] = x*inv; dirc[r][1] = y*inv; dirc[r][2] = zz*inv;
        float cut = (d < RCUT) ? 0.5f*(cosf(PI_F*d/RCUT) + 1.f) : 0.f;
        float s   = sqrtf(2.f/RCUT) * cut * inv;
        float w   = PI_F * d / RCUT;
        #pragma unroll
        for (int b = 0; b < NBASIS; ++b)
            V.de[r][b] = s * sinf((float)(b+1) * w);
        unsigned long long mask = __ballot(head);
        int sid = __popcll(mask & ((1ULL << r) - 1ULL));
        if (head) segrow[sid] = r;
        if (r == 0) nseg_sh = (int)__popcll(mask);
    }
    __syncthreads();

    // ---- P1: msg; segment-flushed atom scatter; Ab = bf16(msg)
    {
        const int f  = tid & 127;
        const int q4 = tid >> 7;                 // rows q4*16 .. +15 (consecutive)
        float mew[NBASIS];
        #pragma unroll
        for (int b = 0; b < NBASIS; ++b) mew[b] = meW[(size_t)f*NBASIS + b];
        int   prev = e0c[q4*16];
        float mv0  = mnp[(size_t)prev*FDIM + f];
        float macc = 0.f;
        #pragma unroll
        for (int i = 0; i < 16; ++i) {
            int r = q4*16 + i;
            int e0 = e0c[r];
            if (e0 != prev) {
                atomicAdd(&atom[(size_t)prev*FDIM + f], macc);
                macc = 0.f; prev = e0;
                mv0 = mnp[(size_t)e0*FDIM + f];
            }
            float m = 0.f;
            if (r < nvalid) {
                float mep = 0.f;
                #pragma unroll
                for (int b = 0; b < NBASIS; ++b) mep += V.de[r][b] * mew[b];
                m = mep * mv0 * mnp[(size_t)e1c[r]*FDIM + f];
                macc += m;
            }
            U.g.Ab[swz(r, f)] = f2bf(m);
        }
        atomicAdd(&atom[(size_t)prev*FDIM + f], macc);
    }
    __syncthreads();        // Ab ready; de dead from here

    f32x4 va1[4], va2[4];

    // ---- G1: Hb0 = silu(msg @ W11^T);  G3: Hb1 = silu(msg @ W21^T)
    #pragma unroll
    for (int n = 0; n < 4; ++n) va1[n] = (f32x4){0.f,0.f,0.f,0.f};
    gemm_g(U.g.Ab, W11pk, mr0, nc0, lane, va1);
    #pragma unroll
    for (int n = 0; n < 4; ++n)
        #pragma unroll
        for (int q = 0; q < 4; ++q)
            U.g.Hb0[swz(mr0 + (lane >> 4)*4 + q, nc0 + n*16 + (lane & 15))] =
                f2bf(silu_f(va1[n][q]));

    #pragma unroll
    for (int n = 0; n < 4; ++n) va2[n] = (f32x4){0.f,0.f,0.f,0.f};
    gemm_g(U.g.Ab, W21pk, mr0, nc0, lane, va2);
    #pragma unroll
    for (int n = 0; n < 4; ++n)
        #pragma unroll
        for (int q = 0; q < 4; ++q)
            V.Hb1[swz(mr0 + (lane >> 4)*4 + q, nc0 + n*16 + (lane & 15))] =
                f2bf(silu_f(va2[n][q]));
    __syncthreads();        // Hb0, Hb1 complete (cross-wave)

    // ---- G2: va1 = h1 @ W12^T;  G4: va2 = h2 @ W22^T
    #pragma unroll
    for (int n = 0; n < 4; ++n) va1[n] = (f32x4){0.f,0.f,0.f,0.f};
    gemm_g(U.g.Hb0, W12pk, mr0, nc0, lane, va1);
    #pragma unroll
    for (int n = 0; n < 4; ++n) va2[n] = (f32x4){0.f,0.f,0.f,0.f};
    gemm_g(V.Hb1, W22pk, mr0, nc0, lane, va2);
    __syncthreads();        // all Ab/Hb reads done -> U.S may overwrite

    // ---- scatter: fnew[e0] += a1*dir + a2*fold[e1], segment-reduced per v
    const int nseg = nseg_sh;
    for (int v = 0; v < 3; ++v) {
        #pragma unroll
        for (int n = 0; n < 4; ++n)
            #pragma unroll
            for (int q = 0; q < 4; ++q) {
                int row = mr0 + (lane >> 4)*4 + q;
                int col = nc0 + n*16 + (lane & 15);
                float fv = fold[(size_t)e1c[row]*3*FDIM + v*FDIM + col];
                U.S[swz4(row, col)] = va1[n][q]*dirc[row][v] + va2[n][q]*fv;
            }
        __syncthreads();
        {
            int col = tid & 127;
            for (int s = tid >> 7; s < nseg; s += 4) {
                int rb = segrow[s];
                int re = (s + 1 < nseg) ? segrow[s+1] : CHUNK;
                float sum = 0.f;
                for (int r = rb; r < re; ++r) sum += U.S[swz4(r, col)];
                atomicAdd(&fnew[(size_t)e0c[rb]*3*FDIM + v*FDIM + col], sum);
            }
        }
        __syncthreads();
    }
}

// ================================================================ node update (MFMA, global B)
__global__ __launch_bounds__(TPB, 6)
void upd_mfma_kernel(const float* __restrict__ fc, const unsigned short* __restrict__ Wpk,
                     float* __restrict__ atom, int R)
{
    __shared__ unsigned short Ab[CHUNK*FDIM];
    const int tid  = threadIdx.x;
    const int lane = tid & 63;
    const int wid  = tid >> 6;
    const int r0   = blockIdx.x * CHUNK;
    const int mr0  = (wid & 3) * 16;
    const int nc0  = (wid >> 2) * 64;

    {
        const float4* g = reinterpret_cast<const float4*>(fc) + (size_t)r0 * (FDIM/4);
        #pragma unroll
        for (int i = 0; i < 4; ++i) {
            int p = tid + i*TPB;
            int r = p >> 5, c4 = p & 31;
            float4 v = make_float4(0.f,0.f,0.f,0.f);
            if (r0 + r < R) v = g[p];
            ushort4 o;
            o.x = f2bf(v.x); o.y = f2bf(v.y); o.z = f2bf(v.z); o.w = f2bf(v.w);
            *reinterpret_cast<ushort4*>(&Ab[swz(r, c4*4)]) = o;
        }
    }
    __syncthreads();

    f32x4 acc[4];
    #pragma unroll
    for (int n = 0; n < 4; ++n) acc[n] = (f32x4){0.f,0.f,0.f,0.f};
    gemm_g(Ab, Wpk, mr0, nc0, lane, acc);

    #pragma unroll
    for (int n = 0; n < 4; ++n)
        #pragma unroll
        for (int q = 0; q < 4; ++q) {
            int row  = mr0 + (lane >> 4)*4 + q;
            int col  = nc0 + n*16 + (lane & 15);
            int grow = r0 + row;
            if (grow < R) {
                float fv = fc[(size_t)grow*FDIM + col];
                atomicAdd(&atom[(size_t)(grow/3)*FDIM + col], acc[n][q] * fv);
            }
        }
}

// ---------------------------------------------------------------- launch
extern "C" void kernel_launch(void* const* d_in, const int* in_sizes, int n_in,
                              void* d_out, int out_size, void* d_ws, size_t ws_size,
                              hipStream_t stream)
{
    const int*   zc    = (const int*)d_in[0];
    const float* disp  = (const float*)d_in[1];
    const int*   ei    = (const int*)d_in[2];
    const float* emb   = (const float*)d_in[4];
    const float* mnpW1 = (const float*)d_in[5];
    const float* mnpb1 = (const float*)d_in[6];
    const float* mnpW2 = (const float*)d_in[7];
    const float* mnpb2 = (const float*)d_in[8];
    const float* meW   = (const float*)d_in[9];
    const float* eq1W1 = (const float*)d_in[10];
    const float* eq1W2 = (const float*)d_in[11];
    const float* eq2W1 = (const float*)d_in[12];
    const float* eq2W2 = (const float*)d_in[13];
    const float* updW  = (const float*)d_in[14];

    const int N = in_sizes[0];
    const int E = in_sizes[1] / 3;
    const int* ei0 = ei;
    const int* ei1 = ei + E;

    float* atom = (float*)d_out;                      // [N,F]
    float* fB   = (float*)d_out + (size_t)N * FDIM;   // [N,3,F] (final force)

    float* ws   = (float*)d_ws;                       // ~50 MB total
    float* mnp   = ws;  ws += (size_t)N * FDIM;
    float* fA    = ws;  ws += (size_t)N * 3 * FDIM;
    float* sdisp = ws;  ws += (size_t)E * 3;
    unsigned short* wpk = (unsigned short*)ws;        // 21 x 128x128 bf16 (packed)
    ws += (21 * FDIM * FDIM) / 2;
    int*   hist  = (int*)ws;
    int*   off   = hist + N;
    int*   se0   = off + N + 1;
    int*   se1   = se0 + E;

    const int n4F3 = N * 3 * FDIM / 4;
    const int eb   = (E + 255) / 256;
    const size_t MS = (size_t)FDIM * FDIM / 1;        // ushort elems per packed matrix = 16384

    // one-time: pack weights + sort edges by destination
    pack_w_kernel<<<(21*2048 + 255)/256, 256, 0, stream>>>(
        mnpW1, mnpW2, eq1W1, eq1W2, eq2W1, eq2W2, updW, wpk);
    hipMemsetAsync(hist, 0, (size_t)N * sizeof(int), stream);
    hist_kernel<<<eb, 256, 0, stream>>>(ei0, hist, E);
    prefix_kernel<<<1, 1024, 0, stream>>>(hist, off, N, E);
    scatter_kernel<<<eb, 256, 0, stream>>>(ei0, ei1, disp, off, se0, se1, sdisp, E);

    atom_init_kernel<<<(N*FDIM + 255)/256, 256, 0, stream>>>(zc, emb, atom, N);
    zero4_kernel<<<(n4F3 + 255)/256, 256, 0, stream>>>((float4*)fA, n4F3);

    for (int l = 0; l < NLAYERS; ++l) {
        const float* fold;  float* fnew;
        if      (l == 0) { fold = fA; fnew = fB; }
        else if (l == 1) { fold = fB; fnew = fA; }
        else             { fold = fA; fnew = fB; }

        const unsigned short* Lpk = wpk + (size_t)l * 7 * MS;

        node_mlp_g_kernel<<<(N + CHUNK - 1)/CHUNK, TPB, 0, stream>>>(
            atom, mnp,
            Lpk + 0*MS, mnpb1 + (size_t)l*FDIM,
            Lpk + 1*MS, mnpb2 + (size_t)l*FDIM, N);

        if (l == 0) zero4_kernel<<<(n4F3 + 255)/256, 256, 0, stream>>>((float4*)fnew, n4F3);
        else        copy4_kernel<<<(n4F3 + 255)/256, 256, 0, stream>>>((const float4*)fold, (float4*)fnew, n4F3);

        edge_layer_kernel<<<(E + CHUNK - 1)/CHUNK, TPB, 0, stream>>>(
            sdisp, se0, se1, mnp,
            meW + (size_t)l*FDIM*NBASIS,
            Lpk + 2*MS, Lpk + 3*MS, Lpk + 4*MS, Lpk + 5*MS,
            fold, atom, fnew, E);

        upd_mfma_kernel<<<(3*N + CHUNK - 1)/CHUNK, TPB, 0, stream>>>(
            fnew, Lpk + 6*MS, atom, 3*N);
    }
}